// Round 7
// baseline (927.214 us; speedup 1.0000x reference)
//
#include <hip/hip_runtime.h>
#include <cstdint>

#define B_     4096
#define D_     256
#define KK_    6
#define T_     256
#define DEPTH_ 6
#define C_     8
#define F1     1536   // D*K
#define F2     3072   // 2*F1
#define NROW   1536   // T*DEPTH
#define SPLITK 4
#define KSPL   384    // F1 / SPLITK
#define BK     64
#define NIT    (KSPL / BK)   // 6
#define NFB    24     // F1/64 blocks for prep_att
#define WDPAD  1544   // padded K stride for dense-w LDS (bank-friendly)

using bf16x8 = __attribute__((ext_vector_type(8))) __bf16;
using f32x4  = __attribute__((ext_vector_type(4))) float;

__device__ inline float waveSum(float v) {
#pragma unroll
  for (int m = 32; m; m >>= 1) v += __shfl_xor(v, m, 64);
  return v;
}
__device__ inline int waveSumI(int v) {
#pragma unroll
  for (int m = 32; m; m >>= 1) v += __shfl_xor(v, m, 64);
  return v;
}

__device__ inline unsigned short bf16_bits(float v) {   // round-to-nearest-even
  const unsigned u = __float_as_uint(v);
  return (unsigned short)((u + 0x7FFFu + ((u >> 16) & 1u)) >> 16);
}

__device__ __forceinline__ void gload_lds16(const void* g, void* l) {
  __builtin_amdgcn_global_load_lds(
      (const __attribute__((address_space(1))) unsigned int*)g,
      (__attribute__((address_space(3))) unsigned int*)l, 16, 0, 0);
}

// ---------------------------------------------------------------------------
// K0a: tile-transpose att_W -> w_hi bf16 [T][F1]; partial catt col sums
// ---------------------------------------------------------------------------
__global__ __launch_bounds__(256) void prep_att_kernel(
    const float* __restrict__ att_W,
    __bf16* __restrict__ w_hi,
    float* __restrict__ pc)
{
  const int fblk = blockIdx.x * 64;   // over F1
  const int tblk = blockIdx.y * 64;   // over T
  __shared__ float Wl[64][65], Wh[64][65];
  const int tt = threadIdx.x & 63;
  const int f4 = threadIdx.x >> 6;
#pragma unroll
  for (int r = 0; r < 16; ++r) {
    const int f = r * 4 + f4;
    Wl[f][tt] = att_W[(size_t)(fblk + f) * T_ + tblk + tt];
    Wh[f][tt] = att_W[(size_t)(fblk + f + F1) * T_ + tblk + tt];
  }
  __syncthreads();
  const int t  = threadIdx.x >> 2;
  const int fq = threadIdx.x & 3;
#pragma unroll
  for (int pass = 0; pass < 4; ++pass) {
    const int f0 = pass * 16 + fq * 4;
    alignas(8) __bf16 hv[4];
#pragma unroll
    for (int e = 0; e < 4; ++e)
      hv[e] = (__bf16)(Wl[f0 + e][t] - Wh[f0 + e][t]);
    *(uint2*)&w_hi[(size_t)(tblk + t) * F1 + fblk + f0] = *(const uint2*)hv;
  }
  if (threadIdx.x < 64) {
    float s = 0.f;
#pragma unroll
    for (int f = 0; f < 64; ++f) s += Wh[f][threadIdx.x];
    pc[(size_t)blockIdx.x * T_ + tblk + threadIdx.x] = s;
  }
}

// K0b: catt reduce + zero the per-tree pair counters/cursors
__global__ __launch_bounds__(256) void catt_kernel(
    const float* __restrict__ pc, const float* __restrict__ att_b,
    float* __restrict__ catt, int* __restrict__ tcnt, int* __restrict__ tcur)
{
  const int t = threadIdx.x;
  float s = att_b[t];
  for (int i = 0; i < NFB; ++i) s += pc[(size_t)i * T_ + t];
  catt[t] = s;
  tcnt[t] = 0;
  tcur[t] = 0;
}

// ---------------------------------------------------------------------------
// K1: per-row sparsemax of sel_logits, 1 wave per row, all-register Michelot.
// Output: packed records {u16 idx | bf16 val} + const c.
// ---------------------------------------------------------------------------
__global__ __launch_bounds__(256) void sel_sparsemax_kernel(
    const float* __restrict__ sel_logits,
    unsigned* __restrict__ w_pack,
    int* __restrict__ w_cnt, float* __restrict__ w_c)
{
  const int row  = blockIdx.x * 4 + (threadIdx.x >> 6);
  const int lane = threadIdx.x & 63;
  const float* src = sel_logits + (size_t)row * F2;
  float4 z[12];
#pragma unroll
  for (int q = 0; q < 12; ++q)
    z[q] = *(const float4*)(src + q * 256 + lane * 4);

  float tau = -1e30f, taun = 0.f;
  int cprev = F2 + 1;
  for (int it = 0; it < 64; ++it) {
    float s = 0.f; int c = 0;
#pragma unroll
    for (int q = 0; q < 12; ++q) {
      const float* zq = (const float*)&z[q];
#pragma unroll
      for (int r = 0; r < 4; ++r) {
        const float v = zq[r];
        if (v > tau) { s += v; c++; }
      }
    }
    s = waveSum(s); c = waveSumI(c);
    taun = (s - 1.0f) / (float)c;
    if (c == cprev) break;
    cprev = c; tau = taun;
  }
  tau = taun;

  float chi = 0.f;
  float wv[24];
  int nnz = 0;
#pragma unroll
  for (int q = 0; q < 6; ++q) {
    const float* zlo = (const float*)&z[q];
    const float* zhi = (const float*)&z[q + 6];
#pragma unroll
    for (int r = 0; r < 4; ++r) {
      float lo = zlo[r] - tau; lo = lo > 0.f ? lo : 0.f;
      float hi = zhi[r] - tau; hi = hi > 0.f ? hi : 0.f;
      chi += hi;
      const float w = lo - hi;
      wv[q * 4 + r] = w;
      if (w != 0.f) nnz++;
    }
  }
  const float csum = waveSum(chi);
  if (lane == 0) w_c[row] = csum;

  int incl = nnz;
#pragma unroll
  for (int off = 1; off < 64; off <<= 1) {
    const int n = __shfl_up(incl, off, 64);
    if (lane >= off) incl += n;
  }
  const int tot = __shfl(incl, 63, 64);
  int pos = incl - nnz;
  unsigned* wrow = w_pack + (size_t)row * F1;
#pragma unroll
  for (int q = 0; q < 6; ++q) {
#pragma unroll
    for (int r = 0; r < 4; ++r) {
      const float w = wv[q * 4 + r];
      if (w != 0.f) {
        const unsigned idx = (unsigned)(q * 256 + lane * 4 + r);
        wrow[pos] = (idx << 16) | (unsigned)bf16_bits(w);
        pos++;
      }
    }
  }
  if (lane == 0) w_cnt[row] = tot;
}

// ---------------------------------------------------------------------------
// K2: f = sigmoid((x-thr)*exp(log_beta)) -> bf16 hi/lo pair [B][F1]
// ---------------------------------------------------------------------------
__global__ __launch_bounds__(256) void f_kernel(
    const float* __restrict__ x, const float* __restrict__ thr,
    const float* __restrict__ log_beta,
    __bf16* __restrict__ f_hi, __bf16* __restrict__ f_lo)
{
  const int b = blockIdx.x;
  const int d = threadIdx.x;
  const float xv = x[(size_t)b * D_ + d];
  alignas(4) __bf16 hv[6], lv[6];
#pragma unroll
  for (int k = 0; k < KK_; ++k) {
    const float beta = __expf(log_beta[d * KK_ + k]);
    const float tt = (xv - thr[d * KK_ + k]) * beta;
    const float s = 1.0f / (1.0f + __expf(-tt));
    const __bf16 h = (__bf16)s;
    hv[k] = h;
    lv[k] = (__bf16)(s - (float)h);
  }
  const size_t base = (size_t)b * F1 + d * KK_;
  const unsigned* hp = (const unsigned*)hv;
  const unsigned* lp = (const unsigned*)lv;
  unsigned* dh = (unsigned*)&f_hi[base];
  unsigned* dl = (unsigned*)&f_lo[base];
  dh[0] = hp[0]; dh[1] = hp[1]; dh[2] = hp[2];
  dl[0] = lp[0]; dl[1] = lp[1]; dl[2] = lp[2];
}

// ---------------------------------------------------------------------------
// K3: MFMA GEMM, part[sp][b][t] over K-slice of F1 (bf16 f_hi x w_hi)
// ---------------------------------------------------------------------------
__global__ __launch_bounds__(256) void gemm_mfma_kernel(
    const __bf16* __restrict__ f_hi, const __bf16* __restrict__ w_hi,
    float* __restrict__ part)
{
  __shared__ __bf16 As[2][64 * 64];
  __shared__ __bf16 Bs[2][64 * 64];
  const int bm = blockIdx.x * 64;
  const int bn = blockIdx.y * 64;
  const int sp = blockIdx.z;
  const int tid = threadIdx.x;
  const int wid = tid >> 6, lane = tid & 63;
  const int wr = wid >> 1, wc = wid & 1;

  const int srow = lane >> 3;
  const int skb8 = ((lane & 7) ^ srow) << 3;

  const int l15   = lane & 15;
  const int mask  = (lane & 7) << 4;
  const int khalf = (lane >> 4) << 4;
  int offA[2][2], offB[2][2];
#pragma unroll
  for (int m = 0; m < 2; ++m) {
    const int row = wr * 32 + m * 16 + l15;
#pragma unroll
    for (int s = 0; s < 2; ++s)
      offA[m][s] = row * 128 + (((s << 6) | khalf) ^ mask);
  }
#pragma unroll
  for (int n = 0; n < 2; ++n) {
    const int col = wc * 32 + n * 16 + l15;
#pragma unroll
    for (int s = 0; s < 2; ++s)
      offB[n][s] = col * 128 + (((s << 6) | khalf) ^ mask);
  }

  f32x4 acc[2][2] = {};

  auto stage = [&](int it, int buf) {
    const int kl = sp * KSPL + it * BK;
#pragma unroll
    for (int j = 0; j < 2; ++j) {
      const int q = wid * 2 + j;
      gload_lds16(f_hi + (size_t)(bm + q * 8 + srow) * F1 + kl + skb8, &As[buf][q * 512]);
      gload_lds16(w_hi + (size_t)(bn + q * 8 + srow) * F1 + kl + skb8, &Bs[buf][q * 512]);
    }
  };

  stage(0, 0);
  __syncthreads();
  for (int it = 0; it < NIT; ++it) {
    const int cur = it & 1;
    if (it + 1 < NIT) stage(it + 1, cur ^ 1);
    const char* pa = (const char*)As[cur];
    const char* pb = (const char*)Bs[cur];
#pragma unroll
    for (int s = 0; s < 2; ++s) {
      const bf16x8 a0 = *(const bf16x8*)(pa + offA[0][s]);
      const bf16x8 a1 = *(const bf16x8*)(pa + offA[1][s]);
      const bf16x8 b0 = *(const bf16x8*)(pb + offB[0][s]);
      const bf16x8 b1 = *(const bf16x8*)(pb + offB[1][s]);
      acc[0][0] = __builtin_amdgcn_mfma_f32_16x16x32_bf16(a0, b0, acc[0][0], 0, 0, 0);
      acc[0][1] = __builtin_amdgcn_mfma_f32_16x16x32_bf16(a0, b1, acc[0][1], 0, 0, 0);
      acc[1][0] = __builtin_amdgcn_mfma_f32_16x16x32_bf16(a1, b0, acc[1][0], 0, 0, 0);
      acc[1][1] = __builtin_amdgcn_mfma_f32_16x16x32_bf16(a1, b1, acc[1][1], 0, 0, 0);
    }
    __syncthreads();
  }

  const int r0 = (lane >> 4) << 2;
  float* outp = part + (size_t)sp * B_ * T_;
#pragma unroll
  for (int m = 0; m < 2; ++m)
#pragma unroll
    for (int n = 0; n < 2; ++n)
#pragma unroll
      for (int r = 0; r < 4; ++r)
        outp[(size_t)(bm + wr * 32 + m * 16 + r0 + r) * T_ + (bn + wc * 32 + n * 16 + l15)] =
            acc[m][n][r];
}

// ---------------------------------------------------------------------------
// K4: fused split-K reduce + catt + per-row sparsemax over T=256 + compaction
// + per-tree pair counting (atomic; counts are deterministic)
// ---------------------------------------------------------------------------
__global__ __launch_bounds__(64) void att_sparsemax_kernel(
    const float* __restrict__ part, const float* __restrict__ catt,
    uint2* __restrict__ a_pack, int* __restrict__ a_cnt,
    int* __restrict__ tcnt)
{
  const int b = blockIdx.x;
  const int lane = threadIdx.x;
  float z[4];
#pragma unroll
  for (int j = 0; j < 4; ++j) {
    const int t = lane + 64 * j;
    float s = catt[t];
#pragma unroll
    for (int sp = 0; sp < SPLITK; ++sp)
      s += part[((size_t)sp * B_ + b) * T_ + t];
    z[j] = s;
  }
  float tau = -1e30f, taun = 0.f;
  int cprev = T_ + 1;
  for (int it = 0; it < 40; ++it) {
    float s = 0.f; int c = 0;
#pragma unroll
    for (int j = 0; j < 4; ++j) if (z[j] > tau) { s += z[j]; c++; }
    s = waveSum(s); c = waveSumI(c);
    taun = (s - 1.0f) / (float)c;
    if (c == cprev) break;
    cprev = c; tau = taun;
  }
  tau = taun;
  float av[4]; int nnz = 0;
#pragma unroll
  for (int j = 0; j < 4; ++j) {
    float a = z[j] - tau; av[j] = a > 0.f ? a : 0.f;
    if (av[j] > 0.f) nnz++;
  }
  int incl = nnz;
#pragma unroll
  for (int off = 1; off < 64; off <<= 1) {
    const int n = __shfl_up(incl, off, 64);
    if (lane >= off) incl += n;
  }
  int pos = incl - nnz;
#pragma unroll
  for (int j = 0; j < 4; ++j) {
    if (av[j] > 0.f) {
      const int t = lane + 64 * j;
      a_pack[(size_t)b * T_ + pos] =
          make_uint2(__float_as_uint(av[j]), (unsigned)t);
      atomicAdd(&tcnt[t], 1);
      pos++;
    }
  }
  if (lane == 63) a_cnt[b] = incl;
}

// ---------------------------------------------------------------------------
// K4b: exclusive scan of tcnt -> toff (single block)
// ---------------------------------------------------------------------------
__global__ __launch_bounds__(256) void scan_kernel(
    const int* __restrict__ tcnt, int* __restrict__ toff)
{
  __shared__ int s[256];
  const int tid = threadIdx.x;
  const int own = tcnt[tid];
  s[tid] = own;
  __syncthreads();
  for (int off = 1; off < 256; off <<= 1) {
    int v = 0;
    if (tid >= off) v = s[tid - off];
    __syncthreads();
    s[tid] += v;
    __syncthreads();
  }
  toff[tid] = s[tid] - own;
}

// ---------------------------------------------------------------------------
// K4c: scatter pairs into per-tree lists: pairs[pos] = (b<<8)|i
// ---------------------------------------------------------------------------
__global__ __launch_bounds__(256) void scatter_kernel(
    const uint2* __restrict__ a_pack, const int* __restrict__ a_cnt,
    const int* __restrict__ toff, int* __restrict__ tcur,
    unsigned* __restrict__ pairs)
{
  const int b = blockIdx.x * 256 + threadIdx.x;
  const int n = a_cnt[b];
  for (int i = 0; i < n; ++i) {
    const unsigned t = a_pack[(size_t)b * T_ + i].y;
    const int pos = toff[t] + atomicAdd(&tcur[t], 1);
    pairs[pos] = ((unsigned)b << 8) | (unsigned)i;
  }
}

// ---------------------------------------------------------------------------
// K5a: p_gemm — per tree t: densify w rows into LDS, then MFMA over pair
// chunks of 16: p[pair][d] = clip(w_c + sum_k (f_hi+f_lo)[b]·w[t,d])
// A-frag: per-lane global dwordx4 of f rows; B-frag: LDS dense w (row=d).
// ---------------------------------------------------------------------------
__global__ __launch_bounds__(256) void p_gemm_kernel(
    const __bf16* __restrict__ f_hi, const __bf16* __restrict__ f_lo,
    const unsigned* __restrict__ w_pack, const int* __restrict__ w_cnt,
    const float* __restrict__ w_c,
    const unsigned* __restrict__ pairs, const int* __restrict__ toff,
    const int* __restrict__ tcnt,
    float* __restrict__ p_buf)
{
  const int t = blockIdx.x;
  __shared__ unsigned short Wd[8][WDPAD];
  // zero all 8 rows (rows 6,7 stay zero = padding cols)
  unsigned* wz = (unsigned*)&Wd[0][0];
  for (int i = threadIdx.x; i < 8 * WDPAD / 2; i += 256) wz[i] = 0u;
  __syncthreads();
#pragma unroll
  for (int d = 0; d < DEPTH_; ++d) {
    const int row = t * DEPTH_ + d;
    const int cnt = w_cnt[row];
    const unsigned* wr = w_pack + (size_t)row * F1;
    for (int k = threadIdx.x; k < cnt; k += 256) {
      const unsigned rec = wr[k];
      Wd[d][rec >> 16] = (unsigned short)(rec & 0xFFFFu);
    }
  }
  __syncthreads();

  const int cnt = tcnt[t];
  if (cnt == 0) return;
  const int off = toff[t];
  const int lane = threadIdx.x & 63;
  const int wid  = threadIdx.x >> 6;
  const int col  = lane & 15;
  const int ceff = col < 8 ? col : 7;      // cols 6..15 read zero rows
  const int kb   = (lane >> 4) * 16;       // byte offset within 32-k slice
  const char* brow = (const char*)&Wd[ceff][0] + kb;

  for (int c0 = (blockIdx.y * 4 + wid) * 16; c0 < cnt; c0 += 256) {
    int aidx = c0 + col;
    if (aidx >= cnt) aidx = cnt - 1;
    const unsigned pe = pairs[off + aidx];
    const unsigned ba = pe >> 8;
    const char* arow_h = (const char*)(f_hi + (size_t)ba * F1) + kb;
    const char* arow_l = (const char*)(f_lo + (size_t)ba * F1) + kb;
    f32x4 acc = {};
#pragma unroll 4
    for (int k0 = 0; k0 < F1 * 2; k0 += 64) {
      const bf16x8 av = *(const bf16x8*)(arow_h + k0);
      const bf16x8 bv = *(const bf16x8*)(brow + k0);
      acc = __builtin_amdgcn_mfma_f32_16x16x32_bf16(av, bv, acc, 0, 0, 0);
    }
#pragma unroll 4
    for (int k0 = 0; k0 < F1 * 2; k0 += 64) {
      const bf16x8 av = *(const bf16x8*)(arow_l + k0);
      const bf16x8 bv = *(const bf16x8*)(brow + k0);
      acc = __builtin_amdgcn_mfma_f32_16x16x32_bf16(av, bv, acc, 0, 0, 0);
    }
    if (col < DEPTH_) {
      const float wc = w_c[t * DEPTH_ + col];
      const int r0 = (lane >> 4) * 4;
#pragma unroll
      for (int r = 0; r < 4; ++r) {
        const int pidx = c0 + r0 + r;
        if (pidx < cnt) {
          const unsigned pe2 = pairs[off + pidx];
          const unsigned b2 = pe2 >> 8, i2 = pe2 & 255u;
          float pv = wc + acc[r];
          pv = pv < 1e-6f ? 1e-6f : (pv > 1.0f - 1e-6f ? 1.0f - 1e-6f : pv);
          p_buf[((size_t)b2 * T_ + i2) * DEPTH_ + col] = pv;
        }
      }
    }
  }
}

// ---------------------------------------------------------------------------
// K5b: epilogue — out[b,c] = sum_i a_i * sum_l prob_l(p_buf[b,i,:]) * leaf
// ---------------------------------------------------------------------------
__global__ __launch_bounds__(256) void epilogue_kernel(
    const float* __restrict__ p_buf,
    const uint2* __restrict__ a_pack, const int* __restrict__ a_cnt,
    const float* __restrict__ leaf, float* __restrict__ out)
{
  const int b = blockIdx.x;
  __shared__ float oacc[4][C_];
  const int tid = threadIdx.x;
  const int wid = tid >> 6, lane = tid & 63;
  const int nact = a_cnt[b];
  float o[C_];
#pragma unroll
  for (int c = 0; c < C_; ++c) o[c] = 0.f;

  for (int i = wid; i < nact; i += 4) {
    const uint2 ap = a_pack[(size_t)b * T_ + i];
    const float* pp = p_buf + ((size_t)b * T_ + i) * DEPTH_;
    float prob = __uint_as_float(ap.x);
#pragma unroll
    for (int d = 0; d < DEPTH_; ++d) {
      const float pv = pp[d];
      prob *= ((lane >> d) & 1) ? pv : (1.0f - pv);
    }
    const float* lf = leaf + ((size_t)ap.y * 64 + lane) * C_;
#pragma unroll
    for (int c = 0; c < C_; ++c) o[c] += prob * lf[c];
  }
#pragma unroll
  for (int c = 0; c < C_; ++c) o[c] = waveSum(o[c]);
  if (lane == 0) {
#pragma unroll
    for (int c = 0; c < C_; ++c) oacc[wid][c] = o[c];
  }
  __syncthreads();
  if (tid < C_)
    out[(size_t)b * C_ + tid] = oacc[0][tid] + oacc[1][tid] + oacc[2][tid] + oacc[3][tid];
}

// ---------------------------------------------------------------------------
extern "C" void kernel_launch(void* const* d_in, const int* in_sizes, int n_in,
                              void* d_out, int out_size, void* d_ws, size_t ws_size,
                              hipStream_t stream)
{
  const float* x        = (const float*)d_in[0];
  const float* thr      = (const float*)d_in[1];
  const float* log_beta = (const float*)d_in[2];
  const float* sel      = (const float*)d_in[3];
  const float* leaf     = (const float*)d_in[4];
  const float* att_W    = (const float*)d_in[5];
  const float* att_b    = (const float*)d_in[6];
  float* out = (float*)d_out;

  char* ws = (char*)d_ws;
  size_t off = 0;
  auto alloc = [&](size_t bytes) {
    char* p = ws + off;
    off = (off + bytes + 255) & ~(size_t)255;
    return p;
  };
  __bf16*         f_hi   = (__bf16*)alloc((size_t)B_ * F1 * 2);          // 12.6 MB
  __bf16*         f_lo   = (__bf16*)alloc((size_t)B_ * F1 * 2);          // 12.6 MB
  __bf16*         w_hi   = (__bf16*)alloc((size_t)T_ * F1 * 2);          //  0.8 MB
  float*          catt   = (float*)alloc((size_t)T_ * 4);
  float*          pc     = (float*)alloc((size_t)NFB * T_ * 4);
  unsigned*       w_pack = (unsigned*)alloc((size_t)NROW * F1 * 4);      //  9.4 MB
  int*            w_cnt  = (int*)alloc((size_t)NROW * 4);
  float*          w_c    = (float*)alloc((size_t)NROW * 4);
  // part (SPLITK*B*T*4 = 16.8 MB) and p_buf (B*T*6*4 = 25.2 MB) are
  // temporally disjoint (part dead after att_sparsemax) -> aliased.
  char*           big    = alloc((size_t)B_ * T_ * DEPTH_ * 4);          // 25.2 MB
  float*          part   = (float*)big;
  float*          p_buf  = (float*)big;
  uint2*          a_pack = (uint2*)alloc((size_t)B_ * T_ * 8);           //  8.4 MB
  int*            a_cnt  = (int*)alloc((size_t)B_ * 4);
  int*            tcnt   = (int*)alloc((size_t)T_ * 4);
  int*            tcur   = (int*)alloc((size_t)T_ * 4);
  int*            toff   = (int*)alloc((size_t)T_ * 4);
  unsigned*       pairs  = (unsigned*)alloc((size_t)B_ * T_ * 4);        //  4.2 MB
  (void)ws_size; (void)in_sizes; (void)n_in; (void)out_size;             // ~74 MB total

  hipLaunchKernelGGL(prep_att_kernel,      dim3(NFB, T_ / 64),        dim3(256), 0, stream, att_W, w_hi, pc);
  hipLaunchKernelGGL(catt_kernel,          dim3(1),                   dim3(256), 0, stream, pc, att_b, catt, tcnt, tcur);
  hipLaunchKernelGGL(sel_sparsemax_kernel, dim3(NROW / 4),            dim3(256), 0, stream, sel, w_pack, w_cnt, w_c);
  hipLaunchKernelGGL(f_kernel,             dim3(B_),                  dim3(256), 0, stream, x, thr, log_beta, f_hi, f_lo);
  hipLaunchKernelGGL(gemm_mfma_kernel,     dim3(B_ / 64, T_ / 64, SPLITK), dim3(256), 0, stream, f_hi, w_hi, part);
  hipLaunchKernelGGL(att_sparsemax_kernel, dim3(B_),                  dim3(64),  0, stream, part, catt, a_pack, a_cnt, tcnt);
  hipLaunchKernelGGL(scan_kernel,          dim3(1),                   dim3(256), 0, stream, tcnt, toff);
  hipLaunchKernelGGL(scatter_kernel,       dim3(B_ / 256),            dim3(256), 0, stream, a_pack, a_cnt, toff, tcur, pairs);
  hipLaunchKernelGGL(p_gemm_kernel,        dim3(T_, 4),               dim3(256), 0, stream, f_hi, f_lo, w_pack, w_cnt, w_c, pairs, toff, tcnt, p_buf);
  hipLaunchKernelGGL(epilogue_kernel,      dim3(B_),                  dim3(256), 0, stream, p_buf, a_pack, a_cnt, leaf, out);
}

// Round 8
// 127.009 us; speedup vs baseline: 7.3004x; 7.3004x over previous
//
#include <hip/hip_runtime.h>
#include <cstdint>

#define B_     4096
#define D_     256
#define KK_    6
#define T_     256
#define DEPTH_ 6
#define C_     8
#define F1     1536   // D*K
#define F2     3072   // 2*F1
#define NROW   1536   // T*DEPTH
#define SPLITK 4
#define KSPL   384    // F1 / SPLITK
#define BK     64
#define NIT    (KSPL / BK)   // 6
#define NFB    24     // F1/64 blocks for prep_att
#define PINVALID 0x80000000u

using bf16x8 = __attribute__((ext_vector_type(8))) __bf16;
using f32x4  = __attribute__((ext_vector_type(4))) float;

__device__ inline float waveSum(float v) {
#pragma unroll
  for (int m = 32; m; m >>= 1) v += __shfl_xor(v, m, 64);
  return v;
}
__device__ inline int waveSumI(int v) {
#pragma unroll
  for (int m = 32; m; m >>= 1) v += __shfl_xor(v, m, 64);
  return v;
}

__device__ inline unsigned short bf16_bits(float v) {   // round-to-nearest-even
  const unsigned u = __float_as_uint(v);
  return (unsigned short)((u + 0x7FFFu + ((u >> 16) & 1u)) >> 16);
}

__device__ __forceinline__ void gload_lds16(const void* g, void* l) {
  __builtin_amdgcn_global_load_lds(
      (const __attribute__((address_space(1))) unsigned int*)g,
      (__attribute__((address_space(3))) unsigned int*)l, 16, 0, 0);
}

// ---------------------------------------------------------------------------
// K0a: tile-transpose att_W -> w_hi bf16 [T][F1]; partial catt col sums
// ---------------------------------------------------------------------------
__global__ __launch_bounds__(256) void prep_att_kernel(
    const float* __restrict__ att_W,
    __bf16* __restrict__ w_hi,
    float* __restrict__ pc)
{
  const int fblk = blockIdx.x * 64;   // over F1
  const int tblk = blockIdx.y * 64;   // over T
  __shared__ float Wl[64][65], Wh[64][65];
  const int tt = threadIdx.x & 63;
  const int f4 = threadIdx.x >> 6;
#pragma unroll
  for (int r = 0; r < 16; ++r) {
    const int f = r * 4 + f4;
    Wl[f][tt] = att_W[(size_t)(fblk + f) * T_ + tblk + tt];
    Wh[f][tt] = att_W[(size_t)(fblk + f + F1) * T_ + tblk + tt];
  }
  __syncthreads();
  const int t  = threadIdx.x >> 2;
  const int fq = threadIdx.x & 3;
#pragma unroll
  for (int pass = 0; pass < 4; ++pass) {
    const int f0 = pass * 16 + fq * 4;
    alignas(8) __bf16 hv[4];
#pragma unroll
    for (int e = 0; e < 4; ++e)
      hv[e] = (__bf16)(Wl[f0 + e][t] - Wh[f0 + e][t]);
    *(uint2*)&w_hi[(size_t)(tblk + t) * F1 + fblk + f0] = *(const uint2*)hv;
  }
  if (threadIdx.x < 64) {
    float s = 0.f;
#pragma unroll
    for (int f = 0; f < 64; ++f) s += Wh[f][threadIdx.x];
    pc[(size_t)blockIdx.x * T_ + tblk + threadIdx.x] = s;
  }
}

__global__ __launch_bounds__(256) void catt_kernel(
    const float* __restrict__ pc, const float* __restrict__ att_b,
    float* __restrict__ catt)
{
  const int t = threadIdx.x;
  float s = att_b[t];
  for (int i = 0; i < NFB; ++i) s += pc[(size_t)i * T_ + t];
  catt[t] = s;
}

// ---------------------------------------------------------------------------
// K1: per-row sparsemax of sel_logits, 1 wave per row, all-register Michelot.
// Output: packed records {u16 idx | bf16 val} + const c.
// ---------------------------------------------------------------------------
__global__ __launch_bounds__(256) void sel_sparsemax_kernel(
    const float* __restrict__ sel_logits,
    unsigned* __restrict__ w_pack,
    int* __restrict__ w_cnt, float* __restrict__ w_c)
{
  const int row  = blockIdx.x * 4 + (threadIdx.x >> 6);
  const int lane = threadIdx.x & 63;
  const float* src = sel_logits + (size_t)row * F2;
  float4 z[12];
#pragma unroll
  for (int q = 0; q < 12; ++q)
    z[q] = *(const float4*)(src + q * 256 + lane * 4);

  float tau = -1e30f, taun = 0.f;
  int cprev = F2 + 1;
  for (int it = 0; it < 64; ++it) {
    float s = 0.f; int c = 0;
#pragma unroll
    for (int q = 0; q < 12; ++q) {
      const float* zq = (const float*)&z[q];
#pragma unroll
      for (int r = 0; r < 4; ++r) {
        const float v = zq[r];
        if (v > tau) { s += v; c++; }
      }
    }
    s = waveSum(s); c = waveSumI(c);
    taun = (s - 1.0f) / (float)c;
    if (c == cprev) break;
    cprev = c; tau = taun;
  }
  tau = taun;

  float chi = 0.f;
  float wv[24];
  int nnz = 0;
#pragma unroll
  for (int q = 0; q < 6; ++q) {
    const float* zlo = (const float*)&z[q];
    const float* zhi = (const float*)&z[q + 6];
#pragma unroll
    for (int r = 0; r < 4; ++r) {
      float lo = zlo[r] - tau; lo = lo > 0.f ? lo : 0.f;
      float hi = zhi[r] - tau; hi = hi > 0.f ? hi : 0.f;
      chi += hi;
      const float w = lo - hi;
      wv[q * 4 + r] = w;
      if (w != 0.f) nnz++;
    }
  }
  const float csum = waveSum(chi);
  if (lane == 0) w_c[row] = csum;

  int incl = nnz;
#pragma unroll
  for (int off = 1; off < 64; off <<= 1) {
    const int n = __shfl_up(incl, off, 64);
    if (lane >= off) incl += n;
  }
  const int tot = __shfl(incl, 63, 64);
  int pos = incl - nnz;
  unsigned* wrow = w_pack + (size_t)row * F1;
#pragma unroll
  for (int q = 0; q < 6; ++q) {
#pragma unroll
    for (int r = 0; r < 4; ++r) {
      const float w = wv[q * 4 + r];
      if (w != 0.f) {
        const unsigned idx = (unsigned)(q * 256 + lane * 4 + r);
        wrow[pos] = (idx << 16) | (unsigned)bf16_bits(w);
        pos++;
      }
    }
  }
  if (lane == 0) w_cnt[row] = tot;
}

// ---------------------------------------------------------------------------
// K1b: densify w_pack rows into global w_dense[t][8][F1] (rows 6,7 = zeros)
// ---------------------------------------------------------------------------
__global__ __launch_bounds__(256) void dense_w_kernel(
    const unsigned* __restrict__ w_pack, const int* __restrict__ w_cnt,
    __bf16* __restrict__ w_dense)
{
  const int t = blockIdx.x;
  unsigned short* dst = (unsigned short*)(w_dense + (size_t)t * 8 * F1);
  unsigned* dz = (unsigned*)dst;
  for (int i = threadIdx.x; i < 8 * F1 / 2; i += 256) dz[i] = 0u;
  __syncthreads();   // block-level fence: zeros visible before scatter
#pragma unroll
  for (int d = 0; d < DEPTH_; ++d) {
    const int row = t * DEPTH_ + d;
    const int cnt = w_cnt[row];
    const unsigned* wr = w_pack + (size_t)row * F1;
    for (int k = threadIdx.x; k < cnt; k += 256) {
      const unsigned rec = wr[k];
      dst[d * F1 + (rec >> 16)] = (unsigned short)(rec & 0xFFFFu);
    }
  }
}

// ---------------------------------------------------------------------------
// K2: f = sigmoid((x-thr)*exp(log_beta)) -> bf16 hi/lo pair [B][F1]
// ---------------------------------------------------------------------------
__global__ __launch_bounds__(256) void f_kernel(
    const float* __restrict__ x, const float* __restrict__ thr,
    const float* __restrict__ log_beta,
    __bf16* __restrict__ f_hi, __bf16* __restrict__ f_lo)
{
  const int b = blockIdx.x;
  const int d = threadIdx.x;
  const float xv = x[(size_t)b * D_ + d];
  alignas(4) __bf16 hv[6], lv[6];
#pragma unroll
  for (int k = 0; k < KK_; ++k) {
    const float beta = __expf(log_beta[d * KK_ + k]);
    const float tt = (xv - thr[d * KK_ + k]) * beta;
    const float s = 1.0f / (1.0f + __expf(-tt));
    const __bf16 h = (__bf16)s;
    hv[k] = h;
    lv[k] = (__bf16)(s - (float)h);
  }
  const size_t base = (size_t)b * F1 + d * KK_;
  const unsigned* hp = (const unsigned*)hv;
  const unsigned* lp = (const unsigned*)lv;
  unsigned* dh = (unsigned*)&f_hi[base];
  unsigned* dl = (unsigned*)&f_lo[base];
  dh[0] = hp[0]; dh[1] = hp[1]; dh[2] = hp[2];
  dl[0] = lp[0]; dl[1] = lp[1]; dl[2] = lp[2];
}

// ---------------------------------------------------------------------------
// K3: MFMA GEMM, part[sp][b][t] over K-slice of F1 (bf16 f_hi x w_hi)
// ---------------------------------------------------------------------------
__global__ __launch_bounds__(256) void gemm_mfma_kernel(
    const __bf16* __restrict__ f_hi, const __bf16* __restrict__ w_hi,
    float* __restrict__ part)
{
  __shared__ __bf16 As[2][64 * 64];
  __shared__ __bf16 Bs[2][64 * 64];
  const int bm = blockIdx.x * 64;
  const int bn = blockIdx.y * 64;
  const int sp = blockIdx.z;
  const int tid = threadIdx.x;
  const int wid = tid >> 6, lane = tid & 63;
  const int wr = wid >> 1, wc = wid & 1;

  const int srow = lane >> 3;
  const int skb8 = ((lane & 7) ^ srow) << 3;

  const int l15   = lane & 15;
  const int mask  = (lane & 7) << 4;
  const int khalf = (lane >> 4) << 4;
  int offA[2][2], offB[2][2];
#pragma unroll
  for (int m = 0; m < 2; ++m) {
    const int row = wr * 32 + m * 16 + l15;
#pragma unroll
    for (int s = 0; s < 2; ++s)
      offA[m][s] = row * 128 + (((s << 6) | khalf) ^ mask);
  }
#pragma unroll
  for (int n = 0; n < 2; ++n) {
    const int col = wc * 32 + n * 16 + l15;
#pragma unroll
    for (int s = 0; s < 2; ++s)
      offB[n][s] = col * 128 + (((s << 6) | khalf) ^ mask);
  }

  f32x4 acc[2][2] = {};

  auto stage = [&](int it, int buf) {
    const int kl = sp * KSPL + it * BK;
#pragma unroll
    for (int j = 0; j < 2; ++j) {
      const int q = wid * 2 + j;
      gload_lds16(f_hi + (size_t)(bm + q * 8 + srow) * F1 + kl + skb8, &As[buf][q * 512]);
      gload_lds16(w_hi + (size_t)(bn + q * 8 + srow) * F1 + kl + skb8, &Bs[buf][q * 512]);
    }
  };

  stage(0, 0);
  __syncthreads();
  for (int it = 0; it < NIT; ++it) {
    const int cur = it & 1;
    if (it + 1 < NIT) stage(it + 1, cur ^ 1);
    const char* pa = (const char*)As[cur];
    const char* pb = (const char*)Bs[cur];
#pragma unroll
    for (int s = 0; s < 2; ++s) {
      const bf16x8 a0 = *(const bf16x8*)(pa + offA[0][s]);
      const bf16x8 a1 = *(const bf16x8*)(pa + offA[1][s]);
      const bf16x8 b0 = *(const bf16x8*)(pb + offB[0][s]);
      const bf16x8 b1 = *(const bf16x8*)(pb + offB[1][s]);
      acc[0][0] = __builtin_amdgcn_mfma_f32_16x16x32_bf16(a0, b0, acc[0][0], 0, 0, 0);
      acc[0][1] = __builtin_amdgcn_mfma_f32_16x16x32_bf16(a0, b1, acc[0][1], 0, 0, 0);
      acc[1][0] = __builtin_amdgcn_mfma_f32_16x16x32_bf16(a1, b0, acc[1][0], 0, 0, 0);
      acc[1][1] = __builtin_amdgcn_mfma_f32_16x16x32_bf16(a1, b1, acc[1][1], 0, 0, 0);
    }
    __syncthreads();
  }

  const int r0 = (lane >> 4) << 2;
  float* outp = part + (size_t)sp * B_ * T_;
#pragma unroll
  for (int m = 0; m < 2; ++m)
#pragma unroll
    for (int n = 0; n < 2; ++n)
#pragma unroll
      for (int r = 0; r < 4; ++r)
        outp[(size_t)(bm + wr * 32 + m * 16 + r0 + r) * T_ + (bn + wc * 32 + n * 16 + l15)] =
            acc[m][n][r];
}

// ---------------------------------------------------------------------------
// K4: fused split-K reduce + catt + per-row sparsemax over T=256 + compaction
// ---------------------------------------------------------------------------
__global__ __launch_bounds__(64) void att_sparsemax_kernel(
    const float* __restrict__ part, const float* __restrict__ catt,
    uint2* __restrict__ a_pack, int* __restrict__ a_cnt)
{
  const int b = blockIdx.x;
  const int lane = threadIdx.x;
  float z[4];
#pragma unroll
  for (int j = 0; j < 4; ++j) {
    const int t = lane + 64 * j;
    float s = catt[t];
#pragma unroll
    for (int sp = 0; sp < SPLITK; ++sp)
      s += part[((size_t)sp * B_ + b) * T_ + t];
    z[j] = s;
  }
  float tau = -1e30f, taun = 0.f;
  int cprev = T_ + 1;
  for (int it = 0; it < 40; ++it) {
    float s = 0.f; int c = 0;
#pragma unroll
    for (int j = 0; j < 4; ++j) if (z[j] > tau) { s += z[j]; c++; }
    s = waveSum(s); c = waveSumI(c);
    taun = (s - 1.0f) / (float)c;
    if (c == cprev) break;
    cprev = c; tau = taun;
  }
  tau = taun;
  float av[4]; int nnz = 0;
#pragma unroll
  for (int j = 0; j < 4; ++j) {
    float a = z[j] - tau; av[j] = a > 0.f ? a : 0.f;
    if (av[j] > 0.f) nnz++;
  }
  int incl = nnz;
#pragma unroll
  for (int off = 1; off < 64; off <<= 1) {
    const int n = __shfl_up(incl, off, 64);
    if (lane >= off) incl += n;
  }
  int pos = incl - nnz;
#pragma unroll
  for (int j = 0; j < 4; ++j) {
    if (av[j] > 0.f) {
      a_pack[(size_t)b * T_ + pos] =
          make_uint2(__float_as_uint(av[j]), (unsigned)(lane + 64 * j));
      pos++;
    }
  }
  if (lane == 63) a_cnt[b] = incl;
}

// ---------------------------------------------------------------------------
// K4b: per-block-of-b histogram of active trees (LDS atomics only)
// ---------------------------------------------------------------------------
__global__ __launch_bounds__(256) void hist_kernel(
    const uint2* __restrict__ a_pack, const int* __restrict__ a_cnt,
    int* __restrict__ phist)
{
  __shared__ int lh[T_];
  lh[threadIdx.x] = 0;
  __syncthreads();
  const int b = blockIdx.x * 256 + threadIdx.x;
  const int n = a_cnt[b];
  for (int i = 0; i < n; ++i)
    atomicAdd(&lh[a_pack[(size_t)b * T_ + i].y], 1);
  __syncthreads();
  phist[blockIdx.x * T_ + threadIdx.x] = lh[threadIdx.x];
}

// ---------------------------------------------------------------------------
// K4c: single-block scan: padded per-tree offsets, per-(blk,t) bases,
// sentinel fill of padding slots, total chunk count.
// ---------------------------------------------------------------------------
__global__ __launch_bounds__(256) void scan_kernel(
    const int* __restrict__ phist, int* __restrict__ gbase,
    unsigned* __restrict__ pairs, int* __restrict__ nchunks)
{
  __shared__ int s[256];
  const int t = threadIdx.x;
  int part[16];
  int tot = 0;
#pragma unroll
  for (int blk = 0; blk < 16; ++blk) { part[blk] = phist[blk * T_ + t]; tot += part[blk]; }
  const int pad = (tot + 15) & ~15;
  s[t] = pad;
  __syncthreads();
  for (int off = 1; off < 256; off <<= 1) {
    int v = (t >= off) ? s[t - off] : 0;
    __syncthreads();
    s[t] += v;
    __syncthreads();
  }
  const int pad_off = s[t] - pad;
  int running = pad_off;
#pragma unroll
  for (int blk = 0; blk < 16; ++blk) { gbase[blk * T_ + t] = running; running += part[blk]; }
  for (int j = tot; j < pad; ++j)
    pairs[pad_off + j] = PINVALID | ((unsigned)t << 20);
  if (t == 255) nchunks[0] = s[255] >> 4;
}

// ---------------------------------------------------------------------------
// K4d: scatter pairs into padded per-tree regions (LDS cursors)
// entry = (t<<20) | (b<<8) | i
// ---------------------------------------------------------------------------
__global__ __launch_bounds__(256) void scatter_kernel(
    const uint2* __restrict__ a_pack, const int* __restrict__ a_cnt,
    const int* __restrict__ gbase, unsigned* __restrict__ pairs)
{
  __shared__ int cur[T_];
  cur[threadIdx.x] = gbase[blockIdx.x * T_ + threadIdx.x];
  __syncthreads();
  const int b = blockIdx.x * 256 + threadIdx.x;
  const int n = a_cnt[b];
  for (int i = 0; i < n; ++i) {
    const unsigned t = a_pack[(size_t)b * T_ + i].y;
    const int pos = atomicAdd(&cur[t], 1);
    pairs[pos] = (t << 20) | ((unsigned)b << 8) | (unsigned)i;
  }
}

// ---------------------------------------------------------------------------
// K5a: flat p-GEMM. Wave w grid-strides over chunks of 16 pairs (same tree).
// A: per-lane f rows (col=lane&15 -> pair). B: w_dense rows (col -> depth).
// K-loop: 24 groups of 4 MFMA, register double-buffered (static indexing).
// ---------------------------------------------------------------------------
__global__ __launch_bounds__(256) void p_gemm_kernel(
    const __bf16* __restrict__ f_hi, const __bf16* __restrict__ f_lo,
    const __bf16* __restrict__ w_dense, const float* __restrict__ w_c,
    const unsigned* __restrict__ pairs, const int* __restrict__ nchunks,
    float* __restrict__ p_buf)
{
  const int lane = threadIdx.x & 63;
  const int wid  = threadIdx.x >> 6;
  const int nch  = nchunks[0];
  const int col  = lane & 15;
  const int ceff = col < 8 ? col : 7;
  const int kb   = (lane >> 4) * 16;   // byte offset of k-slice
  const int nwaves = gridDim.x * 4;

  for (int c = blockIdx.x * 4 + wid; c < nch; c += nwaves) {
    const int off = c * 16;
    const unsigned t = (pairs[off] >> 20) & 255u;   // uniform within chunk
    const unsigned pe = pairs[off + col];
    const unsigned ba = (pe >> 8) & 4095u;
    const char* ah = (const char*)(f_hi + (size_t)ba * F1) + kb;
    const char* al = (const char*)(f_lo + (size_t)ba * F1) + kb;
    const char* bb = (const char*)(w_dense + ((size_t)t * 8 + ceff) * F1) + kb;

    f32x4 acc = {};
    bf16x8 pa0[4], pb0[4], pa1[4], pb1[4];
#pragma unroll
    for (int r = 0; r < 4; ++r) {
      pa0[r] = *(const bf16x8*)(ah + r * 64);
      pb0[r] = *(const bf16x8*)(bb + r * 64);
    }
    // 24 groups: g in [0,24): seg = (g>=12), k = (g%12)*4 + r (k in 0..47)
#pragma unroll
    for (int g = 0; g < 24; ++g) {
      if (g + 1 < 24) {
        const int it = (g + 1) * 4;
        const int seg = it >= 48;
        const int k = it - seg * 48;
        const char* ab = seg ? al : ah;
        if ((g & 1) == 0) {
#pragma unroll
          for (int r = 0; r < 4; ++r) {
            pa1[r] = *(const bf16x8*)(ab + (k + r) * 64);
            pb1[r] = *(const bf16x8*)(bb + (k + r) * 64);
          }
        } else {
#pragma unroll
          for (int r = 0; r < 4; ++r) {
            pa0[r] = *(const bf16x8*)(ab + (k + r) * 64);
            pb0[r] = *(const bf16x8*)(bb + (k + r) * 64);
          }
        }
      }
      if ((g & 1) == 0) {
#pragma unroll
        for (int r = 0; r < 4; ++r)
          acc = __builtin_amdgcn_mfma_f32_16x16x32_bf16(pa0[r], pb0[r], acc, 0, 0, 0);
      } else {
#pragma unroll
        for (int r = 0; r < 4; ++r)
          acc = __builtin_amdgcn_mfma_f32_16x16x32_bf16(pa1[r], pb1[r], acc, 0, 0, 0);
      }
    }

    if (col < DEPTH_) {
      const float wc = w_c[t * DEPTH_ + col];
      const int r0 = (lane >> 4) * 4;
#pragma unroll
      for (int r = 0; r < 4; ++r) {
        const unsigned pe2 = pairs[off + r0 + r];
        if (!(pe2 & PINVALID)) {
          const unsigned b2 = (pe2 >> 8) & 4095u, i2 = pe2 & 255u;
          float pv = wc + acc[r];
          pv = pv < 1e-6f ? 1e-6f : (pv > 1.0f - 1e-6f ? 1.0f - 1e-6f : pv);
          p_buf[((size_t)b2 * T_ + i2) * DEPTH_ + col] = pv;
        }
      }
    }
  }
}

// ---------------------------------------------------------------------------
// K5b: epilogue — out[b,c] = sum_i a_i * sum_l prob_l(p_buf[b,i,:]) * leaf
// ---------------------------------------------------------------------------
__global__ __launch_bounds__(256) void epilogue_kernel(
    const float* __restrict__ p_buf,
    const uint2* __restrict__ a_pack, const int* __restrict__ a_cnt,
    const float* __restrict__ leaf, float* __restrict__ out)
{
  const int b = blockIdx.x;
  __shared__ float oacc[4][C_];
  const int tid = threadIdx.x;
  const int wid = tid >> 6, lane = tid & 63;
  const int nact = a_cnt[b];
  float o[C_];
#pragma unroll
  for (int c = 0; c < C_; ++c) o[c] = 0.f;

  for (int i = wid; i < nact; i += 4) {
    const uint2 ap = a_pack[(size_t)b * T_ + i];
    const float* pp = p_buf + ((size_t)b * T_ + i) * DEPTH_;
    float prob = __uint_as_float(ap.x);
#pragma unroll
    for (int d = 0; d < DEPTH_; ++d) {
      const float pv = pp[d];
      prob *= ((lane >> d) & 1) ? pv : (1.0f - pv);
    }
    const float* lf = leaf + ((size_t)ap.y * 64 + lane) * C_;
#pragma unroll
    for (int c = 0; c < C_; ++c) o[c] += prob * lf[c];
  }
#pragma unroll
  for (int c = 0; c < C_; ++c) o[c] = waveSum(o[c]);
  if (lane == 0) {
#pragma unroll
    for (int c = 0; c < C_; ++c) oacc[wid][c] = o[c];
  }
  __syncthreads();
  if (tid < C_)
    out[(size_t)b * C_ + tid] = oacc[0][tid] + oacc[1][tid] + oacc[2][tid] + oacc[3][tid];
}

// ---------------------------------------------------------------------------
extern "C" void kernel_launch(void* const* d_in, const int* in_sizes, int n_in,
                              void* d_out, int out_size, void* d_ws, size_t ws_size,
                              hipStream_t stream)
{
  const float* x        = (const float*)d_in[0];
  const float* thr      = (const float*)d_in[1];
  const float* log_beta = (const float*)d_in[2];
  const float* sel      = (const float*)d_in[3];
  const float* leaf     = (const float*)d_in[4];
  const float* att_W    = (const float*)d_in[5];
  const float* att_b    = (const float*)d_in[6];
  float* out = (float*)d_out;

  char* ws = (char*)d_ws;
  size_t off = 0;
  auto alloc = [&](size_t bytes) {
    char* p = ws + off;
    off = (off + bytes + 255) & ~(size_t)255;
    return p;
  };
  __bf16*         f_hi    = (__bf16*)alloc((size_t)B_ * F1 * 2);           // 12.6 MB
  __bf16*         f_lo    = (__bf16*)alloc((size_t)B_ * F1 * 2);           // 12.6 MB
  __bf16*         w_hi    = (__bf16*)alloc((size_t)T_ * F1 * 2);           //  0.8 MB
  float*          catt    = (float*)alloc((size_t)T_ * 4);
  float*          pc      = (float*)alloc((size_t)NFB * T_ * 4);
  unsigned*       w_pack  = (unsigned*)alloc((size_t)NROW * F1 * 4);       //  9.4 MB
  int*            w_cnt   = (int*)alloc((size_t)NROW * 4);
  float*          w_c     = (float*)alloc((size_t)NROW * 4);
  __bf16*         w_dense = (__bf16*)alloc((size_t)T_ * 8 * F1 * 2);       //  6.3 MB
  // part (16.8 MB) and p_buf (25.2 MB) are temporally disjoint -> aliased.
  char*           big     = alloc((size_t)B_ * T_ * DEPTH_ * 4);           // 25.2 MB
  float*          part    = (float*)big;
  float*          p_buf   = (float*)big;
  uint2*          a_pack  = (uint2*)alloc((size_t)B_ * T_ * 8);            //  8.4 MB
  int*            a_cnt   = (int*)alloc((size_t)B_ * 4);
  int*            phist   = (int*)alloc((size_t)16 * T_ * 4);
  int*            gbase   = (int*)alloc((size_t)16 * T_ * 4);
  int*            nchunks = (int*)alloc(256);
  unsigned*       pairs   = (unsigned*)alloc(((size_t)B_ * T_ + 16 * T_) * 4); // 4.2 MB
  (void)ws_size; (void)in_sizes; (void)n_in; (void)out_size;               // ~81 MB total

  hipLaunchKernelGGL(prep_att_kernel,      dim3(NFB, T_ / 64),        dim3(256), 0, stream, att_W, w_hi, pc);
  hipLaunchKernelGGL(catt_kernel,          dim3(1),                   dim3(256), 0, stream, pc, att_b, catt);
  hipLaunchKernelGGL(sel_sparsemax_kernel, dim3(NROW / 4),            dim3(256), 0, stream, sel, w_pack, w_cnt, w_c);
  hipLaunchKernelGGL(dense_w_kernel,       dim3(T_),                  dim3(256), 0, stream, w_pack, w_cnt, w_dense);
  hipLaunchKernelGGL(f_kernel,             dim3(B_),                  dim3(256), 0, stream, x, thr, log_beta, f_hi, f_lo);
  hipLaunchKernelGGL(gemm_mfma_kernel,     dim3(B_ / 64, T_ / 64, SPLITK), dim3(256), 0, stream, f_hi, w_hi, part);
  hipLaunchKernelGGL(att_sparsemax_kernel, dim3(B_),                  dim3(64),  0, stream, part, catt, a_pack, a_cnt);
  hipLaunchKernelGGL(hist_kernel,          dim3(B_ / 256),            dim3(256), 0, stream, a_pack, a_cnt, phist);
  hipLaunchKernelGGL(scan_kernel,          dim3(1),                   dim3(256), 0, stream, phist, gbase, pairs, nchunks);
  hipLaunchKernelGGL(scatter_kernel,       dim3(B_ / 256),            dim3(256), 0, stream, a_pack, a_cnt, gbase, pairs);
  hipLaunchKernelGGL(p_gemm_kernel,        dim3(1024),                dim3(256), 0, stream, f_hi, f_lo, w_dense, w_c, pairs, nchunks, p_buf);
  hipLaunchKernelGGL(epilogue_kernel,      dim3(B_),                  dim3(256), 0, stream, p_buf, a_pack, a_cnt, leaf, out);
}

// Round 9
// 121.469 us; speedup vs baseline: 7.6333x; 1.0456x over previous
//
#include <hip/hip_runtime.h>
#include <cstdint>

#define B_     4096
#define D_     256
#define KK_    6
#define T_     256
#define DEPTH_ 6
#define C_     8
#define F1     1536   // D*K
#define F2     3072   // 2*F1
#define NROW   1536   // T*DEPTH
#define SPLITK 4
#define KSPL   384    // F1 / SPLITK
#define BK     64
#define NIT    (KSPL / BK)   // 6
#define NFB    24     // F1/64 blocks for prep_att
#define PINVALID 0x80000000u

using bf16x8 = __attribute__((ext_vector_type(8))) __bf16;
using f32x4  = __attribute__((ext_vector_type(4))) float;

__device__ inline float waveSum(float v) {
#pragma unroll
  for (int m = 32; m; m >>= 1) v += __shfl_xor(v, m, 64);
  return v;
}
__device__ inline int waveSumI(int v) {
#pragma unroll
  for (int m = 32; m; m >>= 1) v += __shfl_xor(v, m, 64);
  return v;
}

__device__ inline unsigned short bf16_bits(float v) {   // round-to-nearest-even
  const unsigned u = __float_as_uint(v);
  return (unsigned short)((u + 0x7FFFu + ((u >> 16) & 1u)) >> 16);
}

__device__ __forceinline__ void gload_lds16(const void* g, void* l) {
  __builtin_amdgcn_global_load_lds(
      (const __attribute__((address_space(1))) unsigned int*)g,
      (__attribute__((address_space(3))) unsigned int*)l, 16, 0, 0);
}

// ---------------------------------------------------------------------------
// K0a: tile-transpose att_W -> w_hi bf16 [T][F1]; partial catt col sums
// ---------------------------------------------------------------------------
__global__ __launch_bounds__(256) void prep_att_kernel(
    const float* __restrict__ att_W,
    __bf16* __restrict__ w_hi,
    float* __restrict__ pc)
{
  const int fblk = blockIdx.x * 64;   // over F1
  const int tblk = blockIdx.y * 64;   // over T
  __shared__ float Wl[64][65], Wh[64][65];
  const int tt = threadIdx.x & 63;
  const int f4 = threadIdx.x >> 6;
#pragma unroll
  for (int r = 0; r < 16; ++r) {
    const int f = r * 4 + f4;
    Wl[f][tt] = att_W[(size_t)(fblk + f) * T_ + tblk + tt];
    Wh[f][tt] = att_W[(size_t)(fblk + f + F1) * T_ + tblk + tt];
  }
  __syncthreads();
  const int t  = threadIdx.x >> 2;
  const int fq = threadIdx.x & 3;
#pragma unroll
  for (int pass = 0; pass < 4; ++pass) {
    const int f0 = pass * 16 + fq * 4;
    alignas(8) __bf16 hv[4];
#pragma unroll
    for (int e = 0; e < 4; ++e)
      hv[e] = (__bf16)(Wl[f0 + e][t] - Wh[f0 + e][t]);
    *(uint2*)&w_hi[(size_t)(tblk + t) * F1 + fblk + f0] = *(const uint2*)hv;
  }
  if (threadIdx.x < 64) {
    float s = 0.f;
#pragma unroll
    for (int f = 0; f < 64; ++f) s += Wh[f][threadIdx.x];
    pc[(size_t)blockIdx.x * T_ + tblk + threadIdx.x] = s;
  }
}

__global__ __launch_bounds__(256) void catt_kernel(
    const float* __restrict__ pc, const float* __restrict__ att_b,
    float* __restrict__ catt)
{
  const int t = threadIdx.x;
  float s = att_b[t];
  for (int i = 0; i < NFB; ++i) s += pc[(size_t)i * T_ + t];
  catt[t] = s;
}

// ---------------------------------------------------------------------------
// K1: per-row sparsemax of sel_logits, 1 wave per row, all-register Michelot.
// Output: packed records {u16 idx | bf16 val} + const c.
// ---------------------------------------------------------------------------
__global__ __launch_bounds__(256) void sel_sparsemax_kernel(
    const float* __restrict__ sel_logits,
    unsigned* __restrict__ w_pack,
    int* __restrict__ w_cnt, float* __restrict__ w_c)
{
  const int row  = blockIdx.x * 4 + (threadIdx.x >> 6);
  const int lane = threadIdx.x & 63;
  const float* src = sel_logits + (size_t)row * F2;
  float4 z[12];
#pragma unroll
  for (int q = 0; q < 12; ++q)
    z[q] = *(const float4*)(src + q * 256 + lane * 4);

  float tau = -1e30f, taun = 0.f;
  int cprev = F2 + 1;
  for (int it = 0; it < 64; ++it) {
    float s = 0.f; int c = 0;
#pragma unroll
    for (int q = 0; q < 12; ++q) {
      const float* zq = (const float*)&z[q];
#pragma unroll
      for (int r = 0; r < 4; ++r) {
        const float v = zq[r];
        if (v > tau) { s += v; c++; }
      }
    }
    s = waveSum(s); c = waveSumI(c);
    taun = (s - 1.0f) / (float)c;
    if (c == cprev) break;
    cprev = c; tau = taun;
  }
  tau = taun;

  float chi = 0.f;
  float wv[24];
  int nnz = 0;
#pragma unroll
  for (int q = 0; q < 6; ++q) {
    const float* zlo = (const float*)&z[q];
    const float* zhi = (const float*)&z[q + 6];
#pragma unroll
    for (int r = 0; r < 4; ++r) {
      float lo = zlo[r] - tau; lo = lo > 0.f ? lo : 0.f;
      float hi = zhi[r] - tau; hi = hi > 0.f ? hi : 0.f;
      chi += hi;
      const float w = lo - hi;
      wv[q * 4 + r] = w;
      if (w != 0.f) nnz++;
    }
  }
  const float csum = waveSum(chi);
  if (lane == 0) w_c[row] = csum;

  int incl = nnz;
#pragma unroll
  for (int off = 1; off < 64; off <<= 1) {
    const int n = __shfl_up(incl, off, 64);
    if (lane >= off) incl += n;
  }
  const int tot = __shfl(incl, 63, 64);
  int pos = incl - nnz;
  unsigned* wrow = w_pack + (size_t)row * F1;
#pragma unroll
  for (int q = 0; q < 6; ++q) {
#pragma unroll
    for (int r = 0; r < 4; ++r) {
      const float w = wv[q * 4 + r];
      if (w != 0.f) {
        const unsigned idx = (unsigned)(q * 256 + lane * 4 + r);
        wrow[pos] = (idx << 16) | (unsigned)bf16_bits(w);
        pos++;
      }
    }
  }
  if (lane == 0) w_cnt[row] = tot;
}

// ---------------------------------------------------------------------------
// K1b: densify w_pack rows into global w_dense[t][8][F1] (rows 6,7 = zeros)
// ---------------------------------------------------------------------------
__global__ __launch_bounds__(256) void dense_w_kernel(
    const unsigned* __restrict__ w_pack, const int* __restrict__ w_cnt,
    __bf16* __restrict__ w_dense)
{
  const int t = blockIdx.x;
  unsigned short* dst = (unsigned short*)(w_dense + (size_t)t * 8 * F1);
  unsigned* dz = (unsigned*)dst;
  for (int i = threadIdx.x; i < 8 * F1 / 2; i += 256) dz[i] = 0u;
  __syncthreads();   // block-level fence: zeros visible before scatter
#pragma unroll
  for (int d = 0; d < DEPTH_; ++d) {
    const int row = t * DEPTH_ + d;
    const int cnt = w_cnt[row];
    const unsigned* wr = w_pack + (size_t)row * F1;
    for (int k = threadIdx.x; k < cnt; k += 256) {
      const unsigned rec = wr[k];
      dst[d * F1 + (rec >> 16)] = (unsigned short)(rec & 0xFFFFu);
    }
  }
}

// ---------------------------------------------------------------------------
// K2: f = sigmoid((x-thr)*exp(log_beta)) -> bf16 hi/lo pair [B][F1]
// ---------------------------------------------------------------------------
__global__ __launch_bounds__(256) void f_kernel(
    const float* __restrict__ x, const float* __restrict__ thr,
    const float* __restrict__ log_beta,
    __bf16* __restrict__ f_hi, __bf16* __restrict__ f_lo)
{
  const int b = blockIdx.x;
  const int d = threadIdx.x;
  const float xv = x[(size_t)b * D_ + d];
  alignas(4) __bf16 hv[6], lv[6];
#pragma unroll
  for (int k = 0; k < KK_; ++k) {
    const float beta = __expf(log_beta[d * KK_ + k]);
    const float tt = (xv - thr[d * KK_ + k]) * beta;
    const float s = 1.0f / (1.0f + __expf(-tt));
    const __bf16 h = (__bf16)s;
    hv[k] = h;
    lv[k] = (__bf16)(s - (float)h);
  }
  const size_t base = (size_t)b * F1 + d * KK_;
  const unsigned* hp = (const unsigned*)hv;
  const unsigned* lp = (const unsigned*)lv;
  unsigned* dh = (unsigned*)&f_hi[base];
  unsigned* dl = (unsigned*)&f_lo[base];
  dh[0] = hp[0]; dh[1] = hp[1]; dh[2] = hp[2];
  dl[0] = lp[0]; dl[1] = lp[1]; dl[2] = lp[2];
}

// ---------------------------------------------------------------------------
// K3: MFMA GEMM, part[sp][b][t] over K-slice of F1 (bf16 f_hi x w_hi)
// ---------------------------------------------------------------------------
__global__ __launch_bounds__(256) void gemm_mfma_kernel(
    const __bf16* __restrict__ f_hi, const __bf16* __restrict__ w_hi,
    float* __restrict__ part)
{
  __shared__ __bf16 As[2][64 * 64];
  __shared__ __bf16 Bs[2][64 * 64];
  const int bm = blockIdx.x * 64;
  const int bn = blockIdx.y * 64;
  const int sp = blockIdx.z;
  const int tid = threadIdx.x;
  const int wid = tid >> 6, lane = tid & 63;
  const int wr = wid >> 1, wc = wid & 1;

  const int srow = lane >> 3;
  const int skb8 = ((lane & 7) ^ srow) << 3;

  const int l15   = lane & 15;
  const int mask  = (lane & 7) << 4;
  const int khalf = (lane >> 4) << 4;
  int offA[2][2], offB[2][2];
#pragma unroll
  for (int m = 0; m < 2; ++m) {
    const int row = wr * 32 + m * 16 + l15;
#pragma unroll
    for (int s = 0; s < 2; ++s)
      offA[m][s] = row * 128 + (((s << 6) | khalf) ^ mask);
  }
#pragma unroll
  for (int n = 0; n < 2; ++n) {
    const int col = wc * 32 + n * 16 + l15;
#pragma unroll
    for (int s = 0; s < 2; ++s)
      offB[n][s] = col * 128 + (((s << 6) | khalf) ^ mask);
  }

  f32x4 acc[2][2] = {};

  auto stage = [&](int it, int buf) {
    const int kl = sp * KSPL + it * BK;
#pragma unroll
    for (int j = 0; j < 2; ++j) {
      const int q = wid * 2 + j;
      gload_lds16(f_hi + (size_t)(bm + q * 8 + srow) * F1 + kl + skb8, &As[buf][q * 512]);
      gload_lds16(w_hi + (size_t)(bn + q * 8 + srow) * F1 + kl + skb8, &Bs[buf][q * 512]);
    }
  };

  stage(0, 0);
  __syncthreads();
  for (int it = 0; it < NIT; ++it) {
    const int cur = it & 1;
    if (it + 1 < NIT) stage(it + 1, cur ^ 1);
    const char* pa = (const char*)As[cur];
    const char* pb = (const char*)Bs[cur];
#pragma unroll
    for (int s = 0; s < 2; ++s) {
      const bf16x8 a0 = *(const bf16x8*)(pa + offA[0][s]);
      const bf16x8 a1 = *(const bf16x8*)(pa + offA[1][s]);
      const bf16x8 b0 = *(const bf16x8*)(pb + offB[0][s]);
      const bf16x8 b1 = *(const bf16x8*)(pb + offB[1][s]);
      acc[0][0] = __builtin_amdgcn_mfma_f32_16x16x32_bf16(a0, b0, acc[0][0], 0, 0, 0);
      acc[0][1] = __builtin_amdgcn_mfma_f32_16x16x32_bf16(a0, b1, acc[0][1], 0, 0, 0);
      acc[1][0] = __builtin_amdgcn_mfma_f32_16x16x32_bf16(a1, b0, acc[1][0], 0, 0, 0);
      acc[1][1] = __builtin_amdgcn_mfma_f32_16x16x32_bf16(a1, b1, acc[1][1], 0, 0, 0);
    }
    __syncthreads();
  }

  const int r0 = (lane >> 4) << 2;
  float* outp = part + (size_t)sp * B_ * T_;
#pragma unroll
  for (int m = 0; m < 2; ++m)
#pragma unroll
    for (int n = 0; n < 2; ++n)
#pragma unroll
      for (int r = 0; r < 4; ++r)
        outp[(size_t)(bm + wr * 32 + m * 16 + r0 + r) * T_ + (bn + wc * 32 + n * 16 + l15)] =
            acc[m][n][r];
}

// ---------------------------------------------------------------------------
// K4: fused split-K reduce + catt + per-row sparsemax over T=256 + compaction
// ---------------------------------------------------------------------------
__global__ __launch_bounds__(64) void att_sparsemax_kernel(
    const float* __restrict__ part, const float* __restrict__ catt,
    uint2* __restrict__ a_pack, int* __restrict__ a_cnt)
{
  const int b = blockIdx.x;
  const int lane = threadIdx.x;
  float z[4];
#pragma unroll
  for (int j = 0; j < 4; ++j) {
    const int t = lane + 64 * j;
    float s = catt[t];
#pragma unroll
    for (int sp = 0; sp < SPLITK; ++sp)
      s += part[((size_t)sp * B_ + b) * T_ + t];
    z[j] = s;
  }
  float tau = -1e30f, taun = 0.f;
  int cprev = T_ + 1;
  for (int it = 0; it < 40; ++it) {
    float s = 0.f; int c = 0;
#pragma unroll
    for (int j = 0; j < 4; ++j) if (z[j] > tau) { s += z[j]; c++; }
    s = waveSum(s); c = waveSumI(c);
    taun = (s - 1.0f) / (float)c;
    if (c == cprev) break;
    cprev = c; tau = taun;
  }
  tau = taun;
  float av[4]; int nnz = 0;
#pragma unroll
  for (int j = 0; j < 4; ++j) {
    float a = z[j] - tau; av[j] = a > 0.f ? a : 0.f;
    if (av[j] > 0.f) nnz++;
  }
  int incl = nnz;
#pragma unroll
  for (int off = 1; off < 64; off <<= 1) {
    const int n = __shfl_up(incl, off, 64);
    if (lane >= off) incl += n;
  }
  int pos = incl - nnz;
#pragma unroll
  for (int j = 0; j < 4; ++j) {
    if (av[j] > 0.f) {
      a_pack[(size_t)b * T_ + pos] =
          make_uint2(__float_as_uint(av[j]), (unsigned)(lane + 64 * j));
      pos++;
    }
  }
  if (lane == 63) a_cnt[b] = incl;
}

// ---------------------------------------------------------------------------
// K4b: per-block-of-b histogram of active trees (LDS atomics only)
// ---------------------------------------------------------------------------
__global__ __launch_bounds__(256) void hist_kernel(
    const uint2* __restrict__ a_pack, const int* __restrict__ a_cnt,
    int* __restrict__ phist)
{
  __shared__ int lh[T_];
  lh[threadIdx.x] = 0;
  __syncthreads();
  const int b = blockIdx.x * 256 + threadIdx.x;
  const int n = a_cnt[b];
  for (int i = 0; i < n; ++i)
    atomicAdd(&lh[a_pack[(size_t)b * T_ + i].y], 1);
  __syncthreads();
  phist[blockIdx.x * T_ + threadIdx.x] = lh[threadIdx.x];
}

// ---------------------------------------------------------------------------
// K4c: single-block scan: padded per-tree offsets, per-(blk,t) bases,
// sentinel fill of padding slots, total chunk count.
// ---------------------------------------------------------------------------
__global__ __launch_bounds__(256) void scan_kernel(
    const int* __restrict__ phist, int* __restrict__ gbase,
    unsigned* __restrict__ pairs, int* __restrict__ nchunks)
{
  __shared__ int s[256];
  const int t = threadIdx.x;
  int part[16];
  int tot = 0;
#pragma unroll
  for (int blk = 0; blk < 16; ++blk) { part[blk] = phist[blk * T_ + t]; tot += part[blk]; }
  const int pad = (tot + 15) & ~15;
  s[t] = pad;
  __syncthreads();
  for (int off = 1; off < 256; off <<= 1) {
    int v = (t >= off) ? s[t - off] : 0;
    __syncthreads();
    s[t] += v;
    __syncthreads();
  }
  const int pad_off = s[t] - pad;
  int running = pad_off;
#pragma unroll
  for (int blk = 0; blk < 16; ++blk) { gbase[blk * T_ + t] = running; running += part[blk]; }
  for (int j = tot; j < pad; ++j)
    pairs[pad_off + j] = PINVALID | ((unsigned)t << 20);
  if (t == 255) nchunks[0] = s[255] >> 4;
}

// ---------------------------------------------------------------------------
// K4d: scatter pairs into padded per-tree regions (LDS cursors)
// entry = (t<<20) | (b<<8) | i
// ---------------------------------------------------------------------------
__global__ __launch_bounds__(256) void scatter_kernel(
    const uint2* __restrict__ a_pack, const int* __restrict__ a_cnt,
    const int* __restrict__ gbase, unsigned* __restrict__ pairs)
{
  __shared__ int cur[T_];
  cur[threadIdx.x] = gbase[blockIdx.x * T_ + threadIdx.x];
  __syncthreads();
  const int b = blockIdx.x * 256 + threadIdx.x;
  const int n = a_cnt[b];
  for (int i = 0; i < n; ++i) {
    const unsigned t = a_pack[(size_t)b * T_ + i].y;
    const int pos = atomicAdd(&cur[t], 1);
    pairs[pos] = (t << 20) | ((unsigned)b << 8) | (unsigned)i;
  }
}

// ---------------------------------------------------------------------------
// K5a: flat p-GEMM, block per chunk (grid-stride). The 96 K-steps (48 hi +
// 48 lo) are split across the 4 waves (24 each, 6 groups of 4 MFMA, register
// double-buffered) -> per-chunk dependent chain is 6 latency units, not 96.
// Waves 1-3 dump partial accs to LDS; wave 0 reduces + writes p_buf.
// ---------------------------------------------------------------------------
__global__ __launch_bounds__(256) void p_gemm_kernel(
    const __bf16* __restrict__ f_hi, const __bf16* __restrict__ f_lo,
    const __bf16* __restrict__ w_dense, const float* __restrict__ w_c,
    const unsigned* __restrict__ pairs, const int* __restrict__ nchunks,
    float* __restrict__ p_buf)
{
  __shared__ float red[3][64 * 4];
  const int lane = threadIdx.x & 63;
  const int wid  = threadIdx.x >> 6;
  const int nch  = nchunks[0];
  const int col  = lane & 15;
  const int ceff = col < 8 ? col : 7;
  const int kb   = (lane >> 4) * 16;     // byte offset within 64B K-step
  const int k0e  = (wid & 1) * 768;      // element offset of this wave's half

  for (int c = blockIdx.x; c < nch; c += gridDim.x) {
    const int off = c * 16;
    const unsigned t = (pairs[off] >> 20) & 255u;   // uniform within chunk
    const unsigned pe = pairs[off + col];
    const unsigned ba = (pe >> 8) & 4095u;
    const __bf16* fsrc = (wid & 2) ? f_lo : f_hi;
    const char* ab = (const char*)(fsrc + (size_t)ba * F1 + k0e) + kb;
    const char* bb = (const char*)(w_dense + ((size_t)t * 8 + ceff) * F1 + k0e) + kb;

    f32x4 acc = {};
    bf16x8 pa0[4], pb0[4], pa1[4], pb1[4];
#pragma unroll
    for (int r = 0; r < 4; ++r) {
      pa0[r] = *(const bf16x8*)(ab + r * 64);
      pb0[r] = *(const bf16x8*)(bb + r * 64);
    }
#pragma unroll
    for (int g = 0; g < 6; ++g) {
      if (g + 1 < 6) {
        const int kbyte = (g + 1) * 256;   // 4 steps * 64B
        if ((g & 1) == 0) {
#pragma unroll
          for (int r = 0; r < 4; ++r) {
            pa1[r] = *(const bf16x8*)(ab + kbyte + r * 64);
            pb1[r] = *(const bf16x8*)(bb + kbyte + r * 64);
          }
        } else {
#pragma unroll
          for (int r = 0; r < 4; ++r) {
            pa0[r] = *(const bf16x8*)(ab + kbyte + r * 64);
            pb0[r] = *(const bf16x8*)(bb + kbyte + r * 64);
          }
        }
      }
      if ((g & 1) == 0) {
#pragma unroll
        for (int r = 0; r < 4; ++r)
          acc = __builtin_amdgcn_mfma_f32_16x16x32_bf16(pa0[r], pb0[r], acc, 0, 0, 0);
      } else {
#pragma unroll
        for (int r = 0; r < 4; ++r)
          acc = __builtin_amdgcn_mfma_f32_16x16x32_bf16(pa1[r], pb1[r], acc, 0, 0, 0);
      }
    }

    if (wid != 0) {
#pragma unroll
      for (int r = 0; r < 4; ++r) red[wid - 1][lane * 4 + r] = acc[r];
    }
    __syncthreads();
    if (wid == 0) {
#pragma unroll
      for (int w = 0; w < 3; ++w)
#pragma unroll
        for (int r = 0; r < 4; ++r) acc[r] += red[w][lane * 4 + r];
      if (col < DEPTH_) {
        const float wc = w_c[t * DEPTH_ + col];
        const int r0 = (lane >> 4) * 4;
#pragma unroll
        for (int r = 0; r < 4; ++r) {
          const unsigned pe2 = pairs[off + r0 + r];
          if (!(pe2 & PINVALID)) {
            const unsigned b2 = (pe2 >> 8) & 4095u, i2 = pe2 & 255u;
            float pv = wc + acc[r];
            pv = pv < 1e-6f ? 1e-6f : (pv > 1.0f - 1e-6f ? 1.0f - 1e-6f : pv);
            p_buf[((size_t)b2 * T_ + i2) * DEPTH_ + col] = pv;
          }
        }
      }
    }
    __syncthreads();   // red reusable next chunk
  }
}

// ---------------------------------------------------------------------------
// K5b: epilogue — out[b,c] = sum_i a_i * sum_l prob_l(p_buf[b,i,:]) * leaf
// ---------------------------------------------------------------------------
__global__ __launch_bounds__(256) void epilogue_kernel(
    const float* __restrict__ p_buf,
    const uint2* __restrict__ a_pack, const int* __restrict__ a_cnt,
    const float* __restrict__ leaf, float* __restrict__ out)
{
  const int b = blockIdx.x;
  __shared__ float oacc[4][C_];
  const int tid = threadIdx.x;
  const int wid = tid >> 6, lane = tid & 63;
  const int nact = a_cnt[b];
  float o[C_];
#pragma unroll
  for (int c = 0; c < C_; ++c) o[c] = 0.f;

  for (int i = wid; i < nact; i += 4) {
    const uint2 ap = a_pack[(size_t)b * T_ + i];
    const float* pp = p_buf + ((size_t)b * T_ + i) * DEPTH_;
    float prob = __uint_as_float(ap.x);
#pragma unroll
    for (int d = 0; d < DEPTH_; ++d) {
      const float pv = pp[d];
      prob *= ((lane >> d) & 1) ? pv : (1.0f - pv);
    }
    const float* lf = leaf + ((size_t)ap.y * 64 + lane) * C_;
#pragma unroll
    for (int c = 0; c < C_; ++c) o[c] += prob * lf[c];
  }
#pragma unroll
  for (int c = 0; c < C_; ++c) o[c] = waveSum(o[c]);
  if (lane == 0) {
#pragma unroll
    for (int c = 0; c < C_; ++c) oacc[wid][c] = o[c];
  }
  __syncthreads();
  if (tid < C_)
    out[(size_t)b * C_ + tid] = oacc[0][tid] + oacc[1][tid] + oacc[2][tid] + oacc[3][tid];
}

// ---------------------------------------------------------------------------
extern "C" void kernel_launch(void* const* d_in, const int* in_sizes, int n_in,
                              void* d_out, int out_size, void* d_ws, size_t ws_size,
                              hipStream_t stream)
{
  const float* x        = (const float*)d_in[0];
  const float* thr      = (const float*)d_in[1];
  const float* log_beta = (const float*)d_in[2];
  const float* sel      = (const float*)d_in[3];
  const float* leaf     = (const float*)d_in[4];
  const float* att_W    = (const float*)d_in[5];
  const float* att_b    = (const float*)d_in[6];
  float* out = (float*)d_out;

  char* ws = (char*)d_ws;
  size_t off = 0;
  auto alloc = [&](size_t bytes) {
    char* p = ws + off;
    off = (off + bytes + 255) & ~(size_t)255;
    return p;
  };
  __bf16*         f_hi    = (__bf16*)alloc((size_t)B_ * F1 * 2);           // 12.6 MB
  __bf16*         f_lo    = (__bf16*)alloc((size_t)B_ * F1 * 2);           // 12.6 MB
  __bf16*         w_hi    = (__bf16*)alloc((size_t)T_ * F1 * 2);           //  0.8 MB
  float*          catt    = (float*)alloc((size_t)T_ * 4);
  float*          pc      = (float*)alloc((size_t)NFB * T_ * 4);
  unsigned*       w_pack  = (unsigned*)alloc((size_t)NROW * F1 * 4);       //  9.4 MB
  int*            w_cnt   = (int*)alloc((size_t)NROW * 4);
  float*          w_c     = (float*)alloc((size_t)NROW * 4);
  __bf16*         w_dense = (__bf16*)alloc((size_t)T_ * 8 * F1 * 2);       //  6.3 MB
  // part (16.8 MB) and p_buf (25.2 MB) are temporally disjoint -> aliased.
  char*           big     = alloc((size_t)B_ * T_ * DEPTH_ * 4);           // 25.2 MB
  float*          part    = (float*)big;
  float*          p_buf   = (float*)big;
  uint2*          a_pack  = (uint2*)alloc((size_t)B_ * T_ * 8);            //  8.4 MB
  int*            a_cnt   = (int*)alloc((size_t)B_ * 4);
  int*            phist   = (int*)alloc((size_t)16 * T_ * 4);
  int*            gbase   = (int*)alloc((size_t)16 * T_ * 4);
  int*            nchunks = (int*)alloc(256);
  unsigned*       pairs   = (unsigned*)alloc(((size_t)B_ * T_ + 16 * T_) * 4); // 4.2 MB
  (void)ws_size; (void)in_sizes; (void)n_in; (void)out_size;               // ~81 MB total

  hipLaunchKernelGGL(prep_att_kernel,      dim3(NFB, T_ / 64),        dim3(256), 0, stream, att_W, w_hi, pc);
  hipLaunchKernelGGL(catt_kernel,          dim3(1),                   dim3(256), 0, stream, pc, att_b, catt);
  hipLaunchKernelGGL(sel_sparsemax_kernel, dim3(NROW / 4),            dim3(256), 0, stream, sel, w_pack, w_cnt, w_c);
  hipLaunchKernelGGL(dense_w_kernel,       dim3(T_),                  dim3(256), 0, stream, w_pack, w_cnt, w_dense);
  hipLaunchKernelGGL(f_kernel,             dim3(B_),                  dim3(256), 0, stream, x, thr, log_beta, f_hi, f_lo);
  hipLaunchKernelGGL(gemm_mfma_kernel,     dim3(B_ / 64, T_ / 64, SPLITK), dim3(256), 0, stream, f_hi, w_hi, part);
  hipLaunchKernelGGL(att_sparsemax_kernel, dim3(B_),                  dim3(64),  0, stream, part, catt, a_pack, a_cnt);
  hipLaunchKernelGGL(hist_kernel,          dim3(B_ / 256),            dim3(256), 0, stream, a_pack, a_cnt, phist);
  hipLaunchKernelGGL(scan_kernel,          dim3(1),                   dim3(256), 0, stream, phist, gbase, pairs, nchunks);
  hipLaunchKernelGGL(scatter_kernel,       dim3(B_ / 256),            dim3(256), 0, stream, a_pack, a_cnt, gbase, pairs);
  hipLaunchKernelGGL(p_gemm_kernel,        dim3(2048),                dim3(256), 0, stream, f_hi, f_lo, w_dense, w_c, pairs, nchunks, p_buf);
  hipLaunchKernelGGL(epilogue_kernel,      dim3(B_),                  dim3(256), 0, stream, p_buf, a_pack, a_cnt, leaf, out);
}

// Round 10
// 104.668 us; speedup vs baseline: 8.8586x; 1.1605x over previous
//
#include <hip/hip_runtime.h>
#include <cstdint>

#define B_     4096
#define D_     256
#define KK_    6
#define T_     256
#define DEPTH_ 6
#define C_     8
#define F1     1536   // D*K
#define F2     3072   // 2*F1
#define NROW   1536   // T*DEPTH
#define SPLITK 2
#define KSPL   768    // F1 / SPLITK
#define BK     64
#define NIT    (KSPL / BK)   // 12
#define NFB    24     // F1/64 blocks for prep_att
#define PINVALID 0x80000000u

using bf16x8 = __attribute__((ext_vector_type(8))) __bf16;
using f32x4  = __attribute__((ext_vector_type(4))) float;

__device__ inline float waveSum(float v) {
#pragma unroll
  for (int m = 32; m; m >>= 1) v += __shfl_xor(v, m, 64);
  return v;
}
__device__ inline int waveSumI(int v) {
#pragma unroll
  for (int m = 32; m; m >>= 1) v += __shfl_xor(v, m, 64);
  return v;
}

__device__ inline unsigned short bf16_bits(float v) {   // round-to-nearest-even
  const unsigned u = __float_as_uint(v);
  return (unsigned short)((u + 0x7FFFu + ((u >> 16) & 1u)) >> 16);
}

__device__ __forceinline__ void gload_lds16(const void* g, void* l) {
  __builtin_amdgcn_global_load_lds(
      (const __attribute__((address_space(1))) unsigned int*)g,
      (__attribute__((address_space(3))) unsigned int*)l, 16, 0, 0);
}

// ---------------------------------------------------------------------------
// K0a: tile-transpose att_W -> w_hi bf16 [T][F1]; partial catt col sums
// ---------------------------------------------------------------------------
__global__ __launch_bounds__(256) void prep_att_kernel(
    const float* __restrict__ att_W,
    __bf16* __restrict__ w_hi,
    float* __restrict__ pc)
{
  const int fblk = blockIdx.x * 64;   // over F1
  const int tblk = blockIdx.y * 64;   // over T
  __shared__ float Wl[64][65], Wh[64][65];
  const int tt = threadIdx.x & 63;
  const int f4 = threadIdx.x >> 6;
#pragma unroll
  for (int r = 0; r < 16; ++r) {
    const int f = r * 4 + f4;
    Wl[f][tt] = att_W[(size_t)(fblk + f) * T_ + tblk + tt];
    Wh[f][tt] = att_W[(size_t)(fblk + f + F1) * T_ + tblk + tt];
  }
  __syncthreads();
  const int t  = threadIdx.x >> 2;
  const int fq = threadIdx.x & 3;
#pragma unroll
  for (int pass = 0; pass < 4; ++pass) {
    const int f0 = pass * 16 + fq * 4;
    alignas(8) __bf16 hv[4];
#pragma unroll
    for (int e = 0; e < 4; ++e)
      hv[e] = (__bf16)(Wl[f0 + e][t] - Wh[f0 + e][t]);
    *(uint2*)&w_hi[(size_t)(tblk + t) * F1 + fblk + f0] = *(const uint2*)hv;
  }
  if (threadIdx.x < 64) {
    float s = 0.f;
#pragma unroll
    for (int f = 0; f < 64; ++f) s += Wh[f][threadIdx.x];
    pc[(size_t)blockIdx.x * T_ + tblk + threadIdx.x] = s;
  }
}

__global__ __launch_bounds__(256) void catt_kernel(
    const float* __restrict__ pc, const float* __restrict__ att_b,
    float* __restrict__ catt)
{
  const int t = threadIdx.x;
  float s = att_b[t];
  for (int i = 0; i < NFB; ++i) s += pc[(size_t)i * T_ + t];
  catt[t] = s;
}

// ---------------------------------------------------------------------------
// K1: per-row sparsemax of sel_logits, 1 wave per row, all-register Michelot.
// Output: packed records {u16 idx | bf16 val} + const c.
// ---------------------------------------------------------------------------
__global__ __launch_bounds__(256) void sel_sparsemax_kernel(
    const float* __restrict__ sel_logits,
    unsigned* __restrict__ w_pack,
    int* __restrict__ w_cnt, float* __restrict__ w_c)
{
  const int row  = blockIdx.x * 4 + (threadIdx.x >> 6);
  const int lane = threadIdx.x & 63;
  const float* src = sel_logits + (size_t)row * F2;
  float4 z[12];
#pragma unroll
  for (int q = 0; q < 12; ++q)
    z[q] = *(const float4*)(src + q * 256 + lane * 4);

  float tau = -1e30f, taun = 0.f;
  int cprev = F2 + 1;
  for (int it = 0; it < 64; ++it) {
    float s = 0.f; int c = 0;
#pragma unroll
    for (int q = 0; q < 12; ++q) {
      const float* zq = (const float*)&z[q];
#pragma unroll
      for (int r = 0; r < 4; ++r) {
        const float v = zq[r];
        if (v > tau) { s += v; c++; }
      }
    }
    s = waveSum(s); c = waveSumI(c);
    taun = (s - 1.0f) / (float)c;
    if (c == cprev) break;
    cprev = c; tau = taun;
  }
  tau = taun;

  float chi = 0.f;
  float wv[24];
  int nnz = 0;
#pragma unroll
  for (int q = 0; q < 6; ++q) {
    const float* zlo = (const float*)&z[q];
    const float* zhi = (const float*)&z[q + 6];
#pragma unroll
    for (int r = 0; r < 4; ++r) {
      float lo = zlo[r] - tau; lo = lo > 0.f ? lo : 0.f;
      float hi = zhi[r] - tau; hi = hi > 0.f ? hi : 0.f;
      chi += hi;
      const float w = lo - hi;
      wv[q * 4 + r] = w;
      if (w != 0.f) nnz++;
    }
  }
  const float csum = waveSum(chi);
  if (lane == 0) w_c[row] = csum;

  int incl = nnz;
#pragma unroll
  for (int off = 1; off < 64; off <<= 1) {
    const int n = __shfl_up(incl, off, 64);
    if (lane >= off) incl += n;
  }
  const int tot = __shfl(incl, 63, 64);
  int pos = incl - nnz;
  unsigned* wrow = w_pack + (size_t)row * F1;
#pragma unroll
  for (int q = 0; q < 6; ++q) {
#pragma unroll
    for (int r = 0; r < 4; ++r) {
      const float w = wv[q * 4 + r];
      if (w != 0.f) {
        const unsigned idx = (unsigned)(q * 256 + lane * 4 + r);
        wrow[pos] = (idx << 16) | (unsigned)bf16_bits(w);
        pos++;
      }
    }
  }
  if (lane == 0) w_cnt[row] = tot;
}

// ---------------------------------------------------------------------------
// K1b: densify w_pack rows into global w_dense[t][8][F1] (rows 6,7 = zeros)
// ---------------------------------------------------------------------------
__global__ __launch_bounds__(256) void dense_w_kernel(
    const unsigned* __restrict__ w_pack, const int* __restrict__ w_cnt,
    __bf16* __restrict__ w_dense)
{
  const int t = blockIdx.x;
  unsigned short* dst = (unsigned short*)(w_dense + (size_t)t * 8 * F1);
  unsigned* dz = (unsigned*)dst;
  for (int i = threadIdx.x; i < 8 * F1 / 2; i += 256) dz[i] = 0u;
  __syncthreads();   // block-level fence: zeros visible before scatter
#pragma unroll
  for (int d = 0; d < DEPTH_; ++d) {
    const int row = t * DEPTH_ + d;
    const int cnt = w_cnt[row];
    const unsigned* wr = w_pack + (size_t)row * F1;
    for (int k = threadIdx.x; k < cnt; k += 256) {
      const unsigned rec = wr[k];
      dst[d * F1 + (rec >> 16)] = (unsigned short)(rec & 0xFFFFu);
    }
  }
}

// ---------------------------------------------------------------------------
// K2: f = sigmoid((x-thr)*exp(log_beta)) -> bf16 hi/lo pair [B][F1]
// (f_lo retained only for potential accuracy fallback; p uses hi only now)
// ---------------------------------------------------------------------------
__global__ __launch_bounds__(256) void f_kernel(
    const float* __restrict__ x, const float* __restrict__ thr,
    const float* __restrict__ log_beta,
    __bf16* __restrict__ f_hi, __bf16* __restrict__ f_lo)
{
  const int b = blockIdx.x;
  const int d = threadIdx.x;
  const float xv = x[(size_t)b * D_ + d];
  alignas(4) __bf16 hv[6], lv[6];
#pragma unroll
  for (int k = 0; k < KK_; ++k) {
    const float beta = __expf(log_beta[d * KK_ + k]);
    const float tt = (xv - thr[d * KK_ + k]) * beta;
    const float s = 1.0f / (1.0f + __expf(-tt));
    const __bf16 h = (__bf16)s;
    hv[k] = h;
    lv[k] = (__bf16)(s - (float)h);
  }
  const size_t base = (size_t)b * F1 + d * KK_;
  const unsigned* hp = (const unsigned*)hv;
  const unsigned* lp = (const unsigned*)lv;
  unsigned* dh = (unsigned*)&f_hi[base];
  unsigned* dl = (unsigned*)&f_lo[base];
  dh[0] = hp[0]; dh[1] = hp[1]; dh[2] = hp[2];
  dl[0] = lp[0]; dl[1] = lp[1]; dl[2] = lp[2];
}

// ---------------------------------------------------------------------------
// K3: MFMA GEMM, part[sp][b][t] over K-slice of F1 (bf16 f_hi x w_hi)
// ---------------------------------------------------------------------------
__global__ __launch_bounds__(256) void gemm_mfma_kernel(
    const __bf16* __restrict__ f_hi, const __bf16* __restrict__ w_hi,
    float* __restrict__ part)
{
  __shared__ __bf16 As[2][64 * 64];
  __shared__ __bf16 Bs[2][64 * 64];
  const int bm = blockIdx.x * 64;
  const int bn = blockIdx.y * 64;
  const int sp = blockIdx.z;
  const int tid = threadIdx.x;
  const int wid = tid >> 6, lane = tid & 63;
  const int wr = wid >> 1, wc = wid & 1;

  const int srow = lane >> 3;
  const int skb8 = ((lane & 7) ^ srow) << 3;

  const int l15   = lane & 15;
  const int mask  = (lane & 7) << 4;
  const int khalf = (lane >> 4) << 4;
  int offA[2][2], offB[2][2];
#pragma unroll
  for (int m = 0; m < 2; ++m) {
    const int row = wr * 32 + m * 16 + l15;
#pragma unroll
    for (int s = 0; s < 2; ++s)
      offA[m][s] = row * 128 + (((s << 6) | khalf) ^ mask);
  }
#pragma unroll
  for (int n = 0; n < 2; ++n) {
    const int col = wc * 32 + n * 16 + l15;
#pragma unroll
    for (int s = 0; s < 2; ++s)
      offB[n][s] = col * 128 + (((s << 6) | khalf) ^ mask);
  }

  f32x4 acc[2][2] = {};

  auto stage = [&](int it, int buf) {
    const int kl = sp * KSPL + it * BK;
#pragma unroll
    for (int j = 0; j < 2; ++j) {
      const int q = wid * 2 + j;
      gload_lds16(f_hi + (size_t)(bm + q * 8 + srow) * F1 + kl + skb8, &As[buf][q * 512]);
      gload_lds16(w_hi + (size_t)(bn + q * 8 + srow) * F1 + kl + skb8, &Bs[buf][q * 512]);
    }
  };

  stage(0, 0);
  __syncthreads();
  for (int it = 0; it < NIT; ++it) {
    const int cur = it & 1;
    if (it + 1 < NIT) stage(it + 1, cur ^ 1);
    const char* pa = (const char*)As[cur];
    const char* pb = (const char*)Bs[cur];
#pragma unroll
    for (int s = 0; s < 2; ++s) {
      const bf16x8 a0 = *(const bf16x8*)(pa + offA[0][s]);
      const bf16x8 a1 = *(const bf16x8*)(pa + offA[1][s]);
      const bf16x8 b0 = *(const bf16x8*)(pb + offB[0][s]);
      const bf16x8 b1 = *(const bf16x8*)(pb + offB[1][s]);
      acc[0][0] = __builtin_amdgcn_mfma_f32_16x16x32_bf16(a0, b0, acc[0][0], 0, 0, 0);
      acc[0][1] = __builtin_amdgcn_mfma_f32_16x16x32_bf16(a0, b1, acc[0][1], 0, 0, 0);
      acc[1][0] = __builtin_amdgcn_mfma_f32_16x16x32_bf16(a1, b0, acc[1][0], 0, 0, 0);
      acc[1][1] = __builtin_amdgcn_mfma_f32_16x16x32_bf16(a1, b1, acc[1][1], 0, 0, 0);
    }
    __syncthreads();
  }

  const int r0 = (lane >> 4) << 2;
  float* outp = part + (size_t)sp * B_ * T_;
#pragma unroll
  for (int m = 0; m < 2; ++m)
#pragma unroll
    for (int n = 0; n < 2; ++n)
#pragma unroll
      for (int r = 0; r < 4; ++r)
        outp[(size_t)(bm + wr * 32 + m * 16 + r0 + r) * T_ + (bn + wc * 32 + n * 16 + l15)] =
            acc[m][n][r];
}

// ---------------------------------------------------------------------------
// K4: fused split-K reduce + catt + per-row sparsemax over T=256 + compaction
// ---------------------------------------------------------------------------
__global__ __launch_bounds__(64) void att_sparsemax_kernel(
    const float* __restrict__ part, const float* __restrict__ catt,
    uint2* __restrict__ a_pack, int* __restrict__ a_cnt)
{
  const int b = blockIdx.x;
  const int lane = threadIdx.x;
  float z[4];
#pragma unroll
  for (int j = 0; j < 4; ++j) {
    const int t = lane + 64 * j;
    float s = catt[t];
#pragma unroll
    for (int sp = 0; sp < SPLITK; ++sp)
      s += part[((size_t)sp * B_ + b) * T_ + t];
    z[j] = s;
  }
  float tau = -1e30f, taun = 0.f;
  int cprev = T_ + 1;
  for (int it = 0; it < 40; ++it) {
    float s = 0.f; int c = 0;
#pragma unroll
    for (int j = 0; j < 4; ++j) if (z[j] > tau) { s += z[j]; c++; }
    s = waveSum(s); c = waveSumI(c);
    taun = (s - 1.0f) / (float)c;
    if (c == cprev) break;
    cprev = c; tau = taun;
  }
  tau = taun;
  float av[4]; int nnz = 0;
#pragma unroll
  for (int j = 0; j < 4; ++j) {
    float a = z[j] - tau; av[j] = a > 0.f ? a : 0.f;
    if (av[j] > 0.f) nnz++;
  }
  int incl = nnz;
#pragma unroll
  for (int off = 1; off < 64; off <<= 1) {
    const int n = __shfl_up(incl, off, 64);
    if (lane >= off) incl += n;
  }
  int pos = incl - nnz;
#pragma unroll
  for (int j = 0; j < 4; ++j) {
    if (av[j] > 0.f) {
      a_pack[(size_t)b * T_ + pos] =
          make_uint2(__float_as_uint(av[j]), (unsigned)(lane + 64 * j));
      pos++;
    }
  }
  if (lane == 63) a_cnt[b] = incl;
}

// ---------------------------------------------------------------------------
// K4b: per-block-of-b histogram of active trees (LDS atomics only)
// ---------------------------------------------------------------------------
__global__ __launch_bounds__(256) void hist_kernel(
    const uint2* __restrict__ a_pack, const int* __restrict__ a_cnt,
    int* __restrict__ phist)
{
  __shared__ int lh[T_];
  lh[threadIdx.x] = 0;
  __syncthreads();
  const int b = blockIdx.x * 256 + threadIdx.x;
  const int n = a_cnt[b];
  for (int i = 0; i < n; ++i)
    atomicAdd(&lh[a_pack[(size_t)b * T_ + i].y], 1);
  __syncthreads();
  phist[blockIdx.x * T_ + threadIdx.x] = lh[threadIdx.x];
}

// ---------------------------------------------------------------------------
// K4c: single-block scan: padded per-tree offsets, per-(blk,t) bases,
// sentinel fill of padding slots, total chunk count.
// ---------------------------------------------------------------------------
__global__ __launch_bounds__(256) void scan_kernel(
    const int* __restrict__ phist, int* __restrict__ gbase,
    unsigned* __restrict__ pairs, int* __restrict__ nchunks)
{
  __shared__ int s[256];
  const int t = threadIdx.x;
  int part[16];
  int tot = 0;
#pragma unroll
  for (int blk = 0; blk < 16; ++blk) { part[blk] = phist[blk * T_ + t]; tot += part[blk]; }
  const int pad = (tot + 15) & ~15;
  s[t] = pad;
  __syncthreads();
  for (int off = 1; off < 256; off <<= 1) {
    int v = (t >= off) ? s[t - off] : 0;
    __syncthreads();
    s[t] += v;
    __syncthreads();
  }
  const int pad_off = s[t] - pad;
  int running = pad_off;
#pragma unroll
  for (int blk = 0; blk < 16; ++blk) { gbase[blk * T_ + t] = running; running += part[blk]; }
  for (int j = tot; j < pad; ++j)
    pairs[pad_off + j] = PINVALID | ((unsigned)t << 20);
  if (t == 255) nchunks[0] = s[255] >> 4;
}

// ---------------------------------------------------------------------------
// K4d: scatter pairs into padded per-tree regions (LDS cursors)
// entry = (t<<20) | (b<<8) | i
// ---------------------------------------------------------------------------
__global__ __launch_bounds__(256) void scatter_kernel(
    const uint2* __restrict__ a_pack, const int* __restrict__ a_cnt,
    const int* __restrict__ gbase, unsigned* __restrict__ pairs)
{
  __shared__ int cur[T_];
  cur[threadIdx.x] = gbase[blockIdx.x * T_ + threadIdx.x];
  __syncthreads();
  const int b = blockIdx.x * 256 + threadIdx.x;
  const int n = a_cnt[b];
  for (int i = 0; i < n; ++i) {
    const unsigned t = a_pack[(size_t)b * T_ + i].y;
    const int pos = atomicAdd(&cur[t], 1);
    pairs[pos] = (t << 20) | ((unsigned)b << 8) | (unsigned)i;
  }
}

// ---------------------------------------------------------------------------
// K5a: flat p-GEMM, block per chunk (grid-stride). K = 1536 (f_hi only),
// split across 4 waves (384 each, 3 register-double-buffered groups of 4
// MFMA). Waves 1-3 dump partial accs to LDS; wave 0 reduces + writes p_buf.
// ---------------------------------------------------------------------------
__global__ __launch_bounds__(256) void p_gemm_kernel(
    const __bf16* __restrict__ f_hi,
    const __bf16* __restrict__ w_dense, const float* __restrict__ w_c,
    const unsigned* __restrict__ pairs, const int* __restrict__ nchunks,
    float* __restrict__ p_buf)
{
  __shared__ float red[3][64 * 4];
  const int lane = threadIdx.x & 63;
  const int wid  = threadIdx.x >> 6;
  const int nch  = nchunks[0];
  const int col  = lane & 15;
  const int ceff = col < 8 ? col : 7;
  const int kb   = (lane >> 4) * 16;     // byte offset within 64B K-step
  const int k0e  = wid * 384;            // element offset of this wave's quarter

  for (int c = blockIdx.x; c < nch; c += gridDim.x) {
    const int off = c * 16;
    const unsigned t = (pairs[off] >> 20) & 255u;   // uniform within chunk
    const unsigned pe = pairs[off + col];
    const unsigned ba = (pe >> 8) & 4095u;
    const char* ab = (const char*)(f_hi + (size_t)ba * F1 + k0e) + kb;
    const char* bb = (const char*)(w_dense + ((size_t)t * 8 + ceff) * F1 + k0e) + kb;

    f32x4 acc = {};
    bf16x8 pa0[4], pb0[4], pa1[4], pb1[4];
#pragma unroll
    for (int r = 0; r < 4; ++r) {
      pa0[r] = *(const bf16x8*)(ab + r * 64);
      pb0[r] = *(const bf16x8*)(bb + r * 64);
    }
#pragma unroll
    for (int g = 0; g < 3; ++g) {
      if (g + 1 < 3) {
        const int kbyte = (g + 1) * 256;   // 4 steps * 64B
        if ((g & 1) == 0) {
#pragma unroll
          for (int r = 0; r < 4; ++r) {
            pa1[r] = *(const bf16x8*)(ab + kbyte + r * 64);
            pb1[r] = *(const bf16x8*)(bb + kbyte + r * 64);
          }
        } else {
#pragma unroll
          for (int r = 0; r < 4; ++r) {
            pa0[r] = *(const bf16x8*)(ab + kbyte + r * 64);
            pb0[r] = *(const bf16x8*)(bb + kbyte + r * 64);
          }
        }
      }
      if ((g & 1) == 0) {
#pragma unroll
        for (int r = 0; r < 4; ++r)
          acc = __builtin_amdgcn_mfma_f32_16x16x32_bf16(pa0[r], pb0[r], acc, 0, 0, 0);
      } else {
#pragma unroll
        for (int r = 0; r < 4; ++r)
          acc = __builtin_amdgcn_mfma_f32_16x16x32_bf16(pa1[r], pb1[r], acc, 0, 0, 0);
      }
    }

    if (wid != 0) {
#pragma unroll
      for (int r = 0; r < 4; ++r) red[wid - 1][lane * 4 + r] = acc[r];
    }
    __syncthreads();
    if (wid == 0) {
#pragma unroll
      for (int w = 0; w < 3; ++w)
#pragma unroll
        for (int r = 0; r < 4; ++r) acc[r] += red[w][lane * 4 + r];
      if (col < DEPTH_) {
        const float wc = w_c[t * DEPTH_ + col];
        const int r0 = (lane >> 4) * 4;
#pragma unroll
        for (int r = 0; r < 4; ++r) {
          const unsigned pe2 = pairs[off + r0 + r];
          if (!(pe2 & PINVALID)) {
            const unsigned b2 = (pe2 >> 8) & 4095u, i2 = pe2 & 255u;
            float pv = wc + acc[r];
            pv = pv < 1e-6f ? 1e-6f : (pv > 1.0f - 1e-6f ? 1.0f - 1e-6f : pv);
            p_buf[((size_t)b2 * T_ + i2) * DEPTH_ + col] = pv;
          }
        }
      }
    }
    __syncthreads();   // red reusable next chunk
  }
}

// ---------------------------------------------------------------------------
// K5b: epilogue — out[b,c] = sum_i a_i * sum_l prob_l(p_buf[b,i,:]) * leaf
// ---------------------------------------------------------------------------
__global__ __launch_bounds__(256) void epilogue_kernel(
    const float* __restrict__ p_buf,
    const uint2* __restrict__ a_pack, const int* __restrict__ a_cnt,
    const float* __restrict__ leaf, float* __restrict__ out)
{
  const int b = blockIdx.x;
  __shared__ float oacc[4][C_];
  const int tid = threadIdx.x;
  const int wid = tid >> 6, lane = tid & 63;
  const int nact = a_cnt[b];
  float o[C_];
#pragma unroll
  for (int c = 0; c < C_; ++c) o[c] = 0.f;

  for (int i = wid; i < nact; i += 4) {
    const uint2 ap = a_pack[(size_t)b * T_ + i];
    const float* pp = p_buf + ((size_t)b * T_ + i) * DEPTH_;
    float prob = __uint_as_float(ap.x);
#pragma unroll
    for (int d = 0; d < DEPTH_; ++d) {
      const float pv = pp[d];
      prob *= ((lane >> d) & 1) ? pv : (1.0f - pv);
    }
    const float* lf = leaf + ((size_t)ap.y * 64 + lane) * C_;
#pragma unroll
    for (int c = 0; c < C_; ++c) o[c] += prob * lf[c];
  }
#pragma unroll
  for (int c = 0; c < C_; ++c) o[c] = waveSum(o[c]);
  if (lane == 0) {
#pragma unroll
    for (int c = 0; c < C_; ++c) oacc[wid][c] = o[c];
  }
  __syncthreads();
  if (tid < C_)
    out[(size_t)b * C_ + tid] = oacc[0][tid] + oacc[1][tid] + oacc[2][tid] + oacc[3][tid];
}

// ---------------------------------------------------------------------------
extern "C" void kernel_launch(void* const* d_in, const int* in_sizes, int n_in,
                              void* d_out, int out_size, void* d_ws, size_t ws_size,
                              hipStream_t stream)
{
  const float* x        = (const float*)d_in[0];
  const float* thr      = (const float*)d_in[1];
  const float* log_beta = (const float*)d_in[2];
  const float* sel      = (const float*)d_in[3];
  const float* leaf     = (const float*)d_in[4];
  const float* att_W    = (const float*)d_in[5];
  const float* att_b    = (const float*)d_in[6];
  float* out = (float*)d_out;

  char* ws = (char*)d_ws;
  size_t off = 0;
  auto alloc = [&](size_t bytes) {
    char* p = ws + off;
    off = (off + bytes + 255) & ~(size_t)255;
    return p;
  };
  __bf16*         f_hi    = (__bf16*)alloc((size_t)B_ * F1 * 2);           // 12.6 MB
  __bf16*         f_lo    = (__bf16*)alloc((size_t)B_ * F1 * 2);           // 12.6 MB
  __bf16*         w_hi    = (__bf16*)alloc((size_t)T_ * F1 * 2);           //  0.8 MB
  float*          catt    = (float*)alloc((size_t)T_ * 4);
  float*          pc      = (float*)alloc((size_t)NFB * T_ * 4);
  unsigned*       w_pack  = (unsigned*)alloc((size_t)NROW * F1 * 4);       //  9.4 MB
  int*            w_cnt   = (int*)alloc((size_t)NROW * 4);
  float*          w_c     = (float*)alloc((size_t)NROW * 4);
  __bf16*         w_dense = (__bf16*)alloc((size_t)T_ * 8 * F1 * 2);       //  6.3 MB
  // part (SPLITK*B*T*4 = 8.4 MB) and p_buf (25.2 MB) temporally disjoint.
  char*           big     = alloc((size_t)B_ * T_ * DEPTH_ * 4);           // 25.2 MB
  float*          part    = (float*)big;
  float*          p_buf   = (float*)big;
  uint2*          a_pack  = (uint2*)alloc((size_t)B_ * T_ * 8);            //  8.4 MB
  int*            a_cnt   = (int*)alloc((size_t)B_ * 4);
  int*            phist   = (int*)alloc((size_t)16 * T_ * 4);
  int*            gbase   = (int*)alloc((size_t)16 * T_ * 4);
  int*            nchunks = (int*)alloc(256);
  unsigned*       pairs   = (unsigned*)alloc(((size_t)B_ * T_ + 16 * T_) * 4); // 4.2 MB
  (void)ws_size; (void)in_sizes; (void)n_in; (void)out_size;               // ~81 MB total

  hipLaunchKernelGGL(prep_att_kernel,      dim3(NFB, T_ / 64),        dim3(256), 0, stream, att_W, w_hi, pc);
  hipLaunchKernelGGL(catt_kernel,          dim3(1),                   dim3(256), 0, stream, pc, att_b, catt);
  hipLaunchKernelGGL(sel_sparsemax_kernel, dim3(NROW / 4),            dim3(256), 0, stream, sel, w_pack, w_cnt, w_c);
  hipLaunchKernelGGL(dense_w_kernel,       dim3(T_),                  dim3(256), 0, stream, w_pack, w_cnt, w_dense);
  hipLaunchKernelGGL(f_kernel,             dim3(B_),                  dim3(256), 0, stream, x, thr, log_beta, f_hi, f_lo);
  hipLaunchKernelGGL(gemm_mfma_kernel,     dim3(B_ / 64, T_ / 64, SPLITK), dim3(256), 0, stream, f_hi, w_hi, part);
  hipLaunchKernelGGL(att_sparsemax_kernel, dim3(B_),                  dim3(64),  0, stream, part, catt, a_pack, a_cnt);
  hipLaunchKernelGGL(hist_kernel,          dim3(B_ / 256),            dim3(256), 0, stream, a_pack, a_cnt, phist);
  hipLaunchKernelGGL(scan_kernel,          dim3(1),                   dim3(256), 0, stream, phist, gbase, pairs, nchunks);
  hipLaunchKernelGGL(scatter_kernel,       dim3(B_ / 256),            dim3(256), 0, stream, a_pack, a_cnt, gbase, pairs);
  hipLaunchKernelGGL(p_gemm_kernel,        dim3(2048),                dim3(256), 0, stream, f_hi, w_dense, w_c, pairs, nchunks, p_buf);
  hipLaunchKernelGGL(epilogue_kernel,      dim3(B_),                  dim3(256), 0, stream, p_buf, a_pack, a_cnt, leaf, out);
}

// Round 11
// 82.824 us; speedup vs baseline: 11.1949x; 1.2637x over previous
//
#include <hip/hip_runtime.h>
#include <cstdint>

#define B_     4096
#define D_     256
#define KK_    6
#define T_     256
#define DEPTH_ 6
#define C_     8
#define F1     1536   // D*K
#define F2     3072   // 2*F1
#define NROW   1536   // T*DEPTH
#define NALL   1792   // 256 att cols + 1536 p cols
#define BK     64
#define NIT    (F1 / BK)    // 24
#define NFB    24     // F1/64 blocks for prep_att

using bf16x8 = __attribute__((ext_vector_type(8))) __bf16;
using f32x4  = __attribute__((ext_vector_type(4))) float;

__device__ inline float waveSum(float v) {
#pragma unroll
  for (int m = 32; m; m >>= 1) v += __shfl_xor(v, m, 64);
  return v;
}
__device__ inline int waveSumI(int v) {
#pragma unroll
  for (int m = 32; m; m >>= 1) v += __shfl_xor(v, m, 64);
  return v;
}

__device__ __forceinline__ void gload_lds16(const void* g, void* l) {
  __builtin_amdgcn_global_load_lds(
      (const __attribute__((address_space(1))) unsigned int*)g,
      (__attribute__((address_space(3))) unsigned int*)l, 16, 0, 0);
}

// ---------------------------------------------------------------------------
// K0a: tile-transpose att_W -> w_all rows 0..255 (bf16); partial catt col sums
// w_all[t][f] = W[f][t] - W[f+F1][t];  pc[fb][t] = sum_{f in blk} W[f+F1][t]
// ---------------------------------------------------------------------------
__global__ __launch_bounds__(256) void prep_att_kernel(
    const float* __restrict__ att_W,
    __bf16* __restrict__ w_all,
    float* __restrict__ pc)
{
  const int fblk = blockIdx.x * 64;   // over F1
  const int tblk = blockIdx.y * 64;   // over T
  __shared__ float Wl[64][65], Wh[64][65];
  const int tt = threadIdx.x & 63;
  const int f4 = threadIdx.x >> 6;
#pragma unroll
  for (int r = 0; r < 16; ++r) {
    const int f = r * 4 + f4;
    Wl[f][tt] = att_W[(size_t)(fblk + f) * T_ + tblk + tt];
    Wh[f][tt] = att_W[(size_t)(fblk + f + F1) * T_ + tblk + tt];
  }
  __syncthreads();
  const int t  = threadIdx.x >> 2;
  const int fq = threadIdx.x & 3;
#pragma unroll
  for (int pass = 0; pass < 4; ++pass) {
    const int f0 = pass * 16 + fq * 4;
    alignas(8) __bf16 hv[4];
#pragma unroll
    for (int e = 0; e < 4; ++e)
      hv[e] = (__bf16)(Wl[f0 + e][t] - Wh[f0 + e][t]);
    *(uint2*)&w_all[(size_t)(tblk + t) * F1 + fblk + f0] = *(const uint2*)hv;
  }
  if (threadIdx.x < 64) {
    float s = 0.f;
#pragma unroll
    for (int f = 0; f < 64; ++f) s += Wh[f][threadIdx.x];
    pc[(size_t)blockIdx.x * T_ + tblk + threadIdx.x] = s;
  }
}

__global__ __launch_bounds__(256) void catt_kernel(
    const float* __restrict__ pc, const float* __restrict__ att_b,
    float* __restrict__ catt)
{
  const int t = threadIdx.x;
  float s = att_b[t];
  for (int i = 0; i < NFB; ++i) s += pc[(size_t)i * T_ + t];
  catt[t] = s;
}

// ---------------------------------------------------------------------------
// K1: per-row sparsemax of sel_logits, 1 wave per row, all-register Michelot.
// Output: DENSE bf16 row into w_all rows 256.. (w[f] = relu(lo)-relu(hi)),
// plus const c = sum relu(hi).  No compaction.
// ---------------------------------------------------------------------------
__global__ __launch_bounds__(256) void sel_sparsemax_kernel(
    const float* __restrict__ sel_logits,
    __bf16* __restrict__ w_all, float* __restrict__ w_c)
{
  const int row  = blockIdx.x * 4 + (threadIdx.x >> 6);
  const int lane = threadIdx.x & 63;
  const float* src = sel_logits + (size_t)row * F2;
  float4 z[12];
#pragma unroll
  for (int q = 0; q < 12; ++q)
    z[q] = *(const float4*)(src + q * 256 + lane * 4);

  float tau = -1e30f, taun = 0.f;
  int cprev = F2 + 1;
  for (int it = 0; it < 64; ++it) {
    float s = 0.f; int c = 0;
#pragma unroll
    for (int q = 0; q < 12; ++q) {
      const float* zq = (const float*)&z[q];
#pragma unroll
      for (int r = 0; r < 4; ++r) {
        const float v = zq[r];
        if (v > tau) { s += v; c++; }
      }
    }
    s = waveSum(s); c = waveSumI(c);
    taun = (s - 1.0f) / (float)c;
    if (c == cprev) break;
    cprev = c; tau = taun;
  }
  tau = taun;

  float chi = 0.f;
  __bf16* wrow = w_all + (size_t)(T_ + row) * F1;
#pragma unroll
  for (int q = 0; q < 6; ++q) {
    const float* zlo = (const float*)&z[q];
    const float* zhi = (const float*)&z[q + 6];
    alignas(8) __bf16 wv[4];
#pragma unroll
    for (int r = 0; r < 4; ++r) {
      float lo = zlo[r] - tau; lo = lo > 0.f ? lo : 0.f;
      float hi = zhi[r] - tau; hi = hi > 0.f ? hi : 0.f;
      chi += hi;
      wv[r] = (__bf16)(lo - hi);
    }
    *(uint2*)&wrow[q * 256 + lane * 4] = *(const uint2*)wv;
  }
  const float csum = waveSum(chi);
  if (lane == 0) w_c[row] = csum;
}

// ---------------------------------------------------------------------------
// K2: f = sigmoid((x-thr)*exp(log_beta)) -> bf16 [B][F1]
// ---------------------------------------------------------------------------
__global__ __launch_bounds__(256) void f_kernel(
    const float* __restrict__ x, const float* __restrict__ thr,
    const float* __restrict__ log_beta,
    __bf16* __restrict__ f_hi)
{
  const int b = blockIdx.x;
  const int d = threadIdx.x;
  const float xv = x[(size_t)b * D_ + d];
  alignas(4) __bf16 hv[6];
#pragma unroll
  for (int k = 0; k < KK_; ++k) {
    const float beta = __expf(log_beta[d * KK_ + k]);
    const float tt = (xv - thr[d * KK_ + k]) * beta;
    const float s = 1.0f / (1.0f + __expf(-tt));
    hv[k] = (__bf16)s;
  }
  const size_t base = (size_t)b * F1 + d * KK_;
  const unsigned* hp = (const unsigned*)hv;
  unsigned* dh = (unsigned*)&f_hi[base];
  dh[0] = hp[0]; dh[1] = hp[1]; dh[2] = hp[2];
}

// ---------------------------------------------------------------------------
// K3: 128x128-tile MFMA GEMM: P[b][n] = sum_k f_hi[b][k] * w_all[n][k]
// M=4096, N=1792, K=1536.  4 waves, each one 64x64 quadrant (4x4 frags of
// 16x16x32), BK=64, double-buffered LDS via global_load_lds w16 + XOR swz.
// ---------------------------------------------------------------------------
__global__ __launch_bounds__(256) void gemm_mfma_kernel(
    const __bf16* __restrict__ f_hi, const __bf16* __restrict__ w_all,
    float* __restrict__ P)
{
  __shared__ __bf16 As[2][128 * 64];
  __shared__ __bf16 Bs[2][128 * 64];
  const int bm = blockIdx.x * 128;
  const int bn = blockIdx.y * 128;
  const int tid = threadIdx.x;
  const int wid = tid >> 6, lane = tid & 63;
  const int wr = wid >> 1, wc = wid & 1;

  const int srow = lane >> 3;                 // 0..7 row within 8-row chunk
  const int skb8 = ((lane & 7) ^ srow) << 3;  // inverse-swizzled src elem off

  const int l15   = lane & 15;
  const int mask  = (lane & 7) << 4;
  const int khalf = (lane >> 4) << 4;
  int offA[4][2], offB[4][2];
#pragma unroll
  for (int m = 0; m < 4; ++m) {
    const int row = wr * 64 + m * 16 + l15;
#pragma unroll
    for (int s = 0; s < 2; ++s)
      offA[m][s] = row * 128 + (((s << 6) | khalf) ^ mask);
  }
#pragma unroll
  for (int n = 0; n < 4; ++n) {
    const int col = wc * 64 + n * 16 + l15;
#pragma unroll
    for (int s = 0; s < 2; ++s)
      offB[n][s] = col * 128 + (((s << 6) | khalf) ^ mask);
  }

  f32x4 acc[4][4] = {};

  auto stage = [&](int it, int buf) {
    const int kl = it * BK;
#pragma unroll
    for (int j = 0; j < 4; ++j) {
      const int q = wid * 4 + j;   // 16 chunks of 8 rows
      gload_lds16(f_hi  + (size_t)(bm + q * 8 + srow) * F1 + kl + skb8, &As[buf][q * 512]);
      gload_lds16(w_all + (size_t)(bn + q * 8 + srow) * F1 + kl + skb8, &Bs[buf][q * 512]);
    }
  };

  stage(0, 0);
  __syncthreads();
  for (int it = 0; it < NIT; ++it) {
    const int cur = it & 1;
    if (it + 1 < NIT) stage(it + 1, cur ^ 1);
    const char* pa = (const char*)As[cur];
    const char* pb = (const char*)Bs[cur];
#pragma unroll
    for (int s = 0; s < 2; ++s) {
      bf16x8 av[4], bv[4];
#pragma unroll
      for (int m = 0; m < 4; ++m) av[m] = *(const bf16x8*)(pa + offA[m][s]);
#pragma unroll
      for (int n = 0; n < 4; ++n) bv[n] = *(const bf16x8*)(pb + offB[n][s]);
#pragma unroll
      for (int m = 0; m < 4; ++m)
#pragma unroll
        for (int n = 0; n < 4; ++n)
          acc[m][n] = __builtin_amdgcn_mfma_f32_16x16x32_bf16(av[m], bv[n], acc[m][n], 0, 0, 0);
    }
    __syncthreads();
  }

  const int r0 = (lane >> 4) << 2;
#pragma unroll
  for (int m = 0; m < 4; ++m)
#pragma unroll
    for (int n = 0; n < 4; ++n)
#pragma unroll
      for (int r = 0; r < 4; ++r)
        P[(size_t)(bm + wr * 64 + m * 16 + r0 + r) * NALL + (bn + wc * 64 + n * 16 + l15)] =
            acc[m][n][r];
}

// ---------------------------------------------------------------------------
// K4: per-row sparsemax over att logits (P cols 0..255) + catt + compaction
// ---------------------------------------------------------------------------
__global__ __launch_bounds__(64) void att_sparsemax_kernel(
    const float* __restrict__ P, const float* __restrict__ catt,
    uint2* __restrict__ a_pack, int* __restrict__ a_cnt)
{
  const int b = blockIdx.x;
  const int lane = threadIdx.x;
  float z[4];
#pragma unroll
  for (int j = 0; j < 4; ++j) {
    const int t = lane + 64 * j;
    z[j] = P[(size_t)b * NALL + t] + catt[t];
  }
  float tau = -1e30f, taun = 0.f;
  int cprev = T_ + 1;
  for (int it = 0; it < 40; ++it) {
    float s = 0.f; int c = 0;
#pragma unroll
    for (int j = 0; j < 4; ++j) if (z[j] > tau) { s += z[j]; c++; }
    s = waveSum(s); c = waveSumI(c);
    taun = (s - 1.0f) / (float)c;
    if (c == cprev) break;
    cprev = c; tau = taun;
  }
  tau = taun;
  float av[4]; int nnz = 0;
#pragma unroll
  for (int j = 0; j < 4; ++j) {
    float a = z[j] - tau; av[j] = a > 0.f ? a : 0.f;
    if (av[j] > 0.f) nnz++;
  }
  int incl = nnz;
#pragma unroll
  for (int off = 1; off < 64; off <<= 1) {
    const int n = __shfl_up(incl, off, 64);
    if (lane >= off) incl += n;
  }
  int pos = incl - nnz;
#pragma unroll
  for (int j = 0; j < 4; ++j) {
    if (av[j] > 0.f) {
      a_pack[(size_t)b * T_ + pos] =
          make_uint2(__float_as_uint(av[j]), (unsigned)(lane + 64 * j));
      pos++;
    }
  }
  if (lane == 63) a_cnt[b] = incl;
}

// ---------------------------------------------------------------------------
// K5: epilogue — p[d] = clip(w_c[t*6+d] + P[b][256+t*6+d]); leaf products.
// ---------------------------------------------------------------------------
__global__ __launch_bounds__(256) void epilogue_kernel(
    const float* __restrict__ P, const float* __restrict__ w_c,
    const uint2* __restrict__ a_pack, const int* __restrict__ a_cnt,
    const float* __restrict__ leaf, float* __restrict__ out)
{
  const int b = blockIdx.x;
  __shared__ float oacc[4][C_];
  const int tid = threadIdx.x;
  const int wid = tid >> 6, lane = tid & 63;
  const int nact = a_cnt[b];
  float o[C_];
#pragma unroll
  for (int c = 0; c < C_; ++c) o[c] = 0.f;

  for (int i = wid; i < nact; i += 4) {
    const uint2 ap = a_pack[(size_t)b * T_ + i];
    const int t = (int)ap.y;
    const float* pp = P + (size_t)b * NALL + T_ + t * DEPTH_;
    const float* wc = w_c + t * DEPTH_;
    float prob = __uint_as_float(ap.x);
#pragma unroll
    for (int d = 0; d < DEPTH_; ++d) {
      float pv = wc[d] + pp[d];
      pv = pv < 1e-6f ? 1e-6f : (pv > 1.0f - 1e-6f ? 1.0f - 1e-6f : pv);
      prob *= ((lane >> d) & 1) ? pv : (1.0f - pv);
    }
    const float* lf = leaf + ((size_t)t * 64 + lane) * C_;
#pragma unroll
    for (int c = 0; c < C_; ++c) o[c] += prob * lf[c];
  }
#pragma unroll
  for (int c = 0; c < C_; ++c) o[c] = waveSum(o[c]);
  if (lane == 0) {
#pragma unroll
    for (int c = 0; c < C_; ++c) oacc[wid][c] = o[c];
  }
  __syncthreads();
  if (tid < C_)
    out[(size_t)b * C_ + tid] = oacc[0][tid] + oacc[1][tid] + oacc[2][tid] + oacc[3][tid];
}

// ---------------------------------------------------------------------------
extern "C" void kernel_launch(void* const* d_in, const int* in_sizes, int n_in,
                              void* d_out, int out_size, void* d_ws, size_t ws_size,
                              hipStream_t stream)
{
  const float* x        = (const float*)d_in[0];
  const float* thr      = (const float*)d_in[1];
  const float* log_beta = (const float*)d_in[2];
  const float* sel      = (const float*)d_in[3];
  const float* leaf     = (const float*)d_in[4];
  const float* att_W    = (const float*)d_in[5];
  const float* att_b    = (const float*)d_in[6];
  float* out = (float*)d_out;

  char* ws = (char*)d_ws;
  size_t off = 0;
  auto alloc = [&](size_t bytes) {
    char* p = ws + off;
    off = (off + bytes + 255) & ~(size_t)255;
    return p;
  };
  __bf16* f_hi   = (__bf16*)alloc((size_t)B_ * F1 * 2);        // 12.6 MB
  __bf16* w_all  = (__bf16*)alloc((size_t)NALL * F1 * 2);      //  5.5 MB
  float*  catt   = (float*)alloc((size_t)T_ * 4);
  float*  pc     = (float*)alloc((size_t)NFB * T_ * 4);
  float*  w_c    = (float*)alloc((size_t)NROW * 4);
  float*  P      = (float*)alloc((size_t)B_ * NALL * 4);       // 29.4 MB
  uint2*  a_pack = (uint2*)alloc((size_t)B_ * T_ * 8);         //  8.4 MB
  int*    a_cnt  = (int*)alloc((size_t)B_ * 4);
  (void)ws_size; (void)in_sizes; (void)n_in; (void)out_size;   // ~56 MB total

  hipLaunchKernelGGL(prep_att_kernel,      dim3(NFB, T_ / 64),      dim3(256), 0, stream, att_W, w_all, pc);
  hipLaunchKernelGGL(catt_kernel,          dim3(1),                 dim3(256), 0, stream, pc, att_b, catt);
  hipLaunchKernelGGL(sel_sparsemax_kernel, dim3(NROW / 4),          dim3(256), 0, stream, sel, w_all, w_c);
  hipLaunchKernelGGL(f_kernel,             dim3(B_),                dim3(256), 0, stream, x, thr, log_beta, f_hi);
  hipLaunchKernelGGL(gemm_mfma_kernel,     dim3(B_ / 128, NALL / 128), dim3(256), 0, stream, f_hi, w_all, P);
  hipLaunchKernelGGL(att_sparsemax_kernel, dim3(B_),                dim3(64),  0, stream, P, catt, a_pack, a_cnt);
  hipLaunchKernelGGL(epilogue_kernel,      dim3(B_),                dim3(256), 0, stream, P, w_c, a_pack, a_cnt, leaf, out);
}

// Round 12
// 81.681 us; speedup vs baseline: 11.3516x; 1.0140x over previous
//
#include <hip/hip_runtime.h>
#include <cstdint>

#define B_     4096
#define D_     256
#define KK_    6
#define T_     256
#define DEPTH_ 6
#define C_     8
#define F1     1536   // D*K
#define F2     3072   // 2*F1
#define NROW   1536   // T*DEPTH
#define NALL   1792   // 256 att cols + 1536 p cols
#define BK     64
#define NIT    (F1 / BK)    // 24
#define NFB    24     // F1/64 blocks for prep_att
#define NBLK   448    // (4096/128) * (1792/128)

using bf16x8 = __attribute__((ext_vector_type(8))) __bf16;
using f32x4  = __attribute__((ext_vector_type(4))) float;

__device__ inline float waveSum(float v) {
#pragma unroll
  for (int m = 32; m; m >>= 1) v += __shfl_xor(v, m, 64);
  return v;
}
__device__ inline int waveSumI(int v) {
#pragma unroll
  for (int m = 32; m; m >>= 1) v += __shfl_xor(v, m, 64);
  return v;
}

__device__ __forceinline__ void gload_lds16(const void* g, void* l) {
  __builtin_amdgcn_global_load_lds(
      (const __attribute__((address_space(1))) unsigned int*)g,
      (__attribute__((address_space(3))) unsigned int*)l, 16, 0, 0);
}

// ---------------------------------------------------------------------------
// K0a: tile-transpose att_W -> w_all rows 0..255 (bf16); partial catt col sums
// ---------------------------------------------------------------------------
__global__ __launch_bounds__(256) void prep_att_kernel(
    const float* __restrict__ att_W,
    __bf16* __restrict__ w_all,
    float* __restrict__ pc)
{
  const int fblk = blockIdx.x * 64;   // over F1
  const int tblk = blockIdx.y * 64;   // over T
  __shared__ float Wl[64][65], Wh[64][65];
  const int tt = threadIdx.x & 63;
  const int f4 = threadIdx.x >> 6;
#pragma unroll
  for (int r = 0; r < 16; ++r) {
    const int f = r * 4 + f4;
    Wl[f][tt] = att_W[(size_t)(fblk + f) * T_ + tblk + tt];
    Wh[f][tt] = att_W[(size_t)(fblk + f + F1) * T_ + tblk + tt];
  }
  __syncthreads();
  const int t  = threadIdx.x >> 2;
  const int fq = threadIdx.x & 3;
#pragma unroll
  for (int pass = 0; pass < 4; ++pass) {
    const int f0 = pass * 16 + fq * 4;
    alignas(8) __bf16 hv[4];
#pragma unroll
    for (int e = 0; e < 4; ++e)
      hv[e] = (__bf16)(Wl[f0 + e][t] - Wh[f0 + e][t]);
    *(uint2*)&w_all[(size_t)(tblk + t) * F1 + fblk + f0] = *(const uint2*)hv;
  }
  if (threadIdx.x < 64) {
    float s = 0.f;
#pragma unroll
    for (int f = 0; f < 64; ++f) s += Wh[f][threadIdx.x];
    pc[(size_t)blockIdx.x * T_ + tblk + threadIdx.x] = s;
  }
}

__global__ __launch_bounds__(256) void catt_kernel(
    const float* __restrict__ pc, const float* __restrict__ att_b,
    float* __restrict__ catt)
{
  const int t = threadIdx.x;
  float s = att_b[t];
  for (int i = 0; i < NFB; ++i) s += pc[(size_t)i * T_ + t];
  catt[t] = s;
}

// ---------------------------------------------------------------------------
// K1: per-row sparsemax of sel_logits, 1 wave per row, all-register Michelot.
// Output: DENSE bf16 row into w_all rows 256.. + const c = sum relu(hi).
// ---------------------------------------------------------------------------
__global__ __launch_bounds__(256) void sel_sparsemax_kernel(
    const float* __restrict__ sel_logits,
    __bf16* __restrict__ w_all, float* __restrict__ w_c)
{
  const int row  = blockIdx.x * 4 + (threadIdx.x >> 6);
  const int lane = threadIdx.x & 63;
  const float* src = sel_logits + (size_t)row * F2;
  float4 z[12];
#pragma unroll
  for (int q = 0; q < 12; ++q)
    z[q] = *(const float4*)(src + q * 256 + lane * 4);

  float tau = -1e30f, taun = 0.f;
  int cprev = F2 + 1;
  for (int it = 0; it < 64; ++it) {
    float s = 0.f; int c = 0;
#pragma unroll
    for (int q = 0; q < 12; ++q) {
      const float* zq = (const float*)&z[q];
#pragma unroll
      for (int r = 0; r < 4; ++r) {
        const float v = zq[r];
        if (v > tau) { s += v; c++; }
      }
    }
    s = waveSum(s); c = waveSumI(c);
    taun = (s - 1.0f) / (float)c;
    if (c == cprev) break;
    cprev = c; tau = taun;
  }
  tau = taun;

  float chi = 0.f;
  __bf16* wrow = w_all + (size_t)(T_ + row) * F1;
#pragma unroll
  for (int q = 0; q < 6; ++q) {
    const float* zlo = (const float*)&z[q];
    const float* zhi = (const float*)&z[q + 6];
    alignas(8) __bf16 wv[4];
#pragma unroll
    for (int r = 0; r < 4; ++r) {
      float lo = zlo[r] - tau; lo = lo > 0.f ? lo : 0.f;
      float hi = zhi[r] - tau; hi = hi > 0.f ? hi : 0.f;
      chi += hi;
      wv[r] = (__bf16)(lo - hi);
    }
    *(uint2*)&wrow[q * 256 + lane * 4] = *(const uint2*)wv;
  }
  const float csum = waveSum(chi);
  if (lane == 0) w_c[row] = csum;
}

// ---------------------------------------------------------------------------
// K2: f = sigmoid((x-thr)*exp(log_beta)) -> bf16 [B][F1]
// ---------------------------------------------------------------------------
__global__ __launch_bounds__(256) void f_kernel(
    const float* __restrict__ x, const float* __restrict__ thr,
    const float* __restrict__ log_beta,
    __bf16* __restrict__ f_hi)
{
  const int b = blockIdx.x;
  const int d = threadIdx.x;
  const float xv = x[(size_t)b * D_ + d];
  alignas(4) __bf16 hv[6];
#pragma unroll
  for (int k = 0; k < KK_; ++k) {
    const float beta = __expf(log_beta[d * KK_ + k]);
    const float tt = (xv - thr[d * KK_ + k]) * beta;
    const float s = 1.0f / (1.0f + __expf(-tt));
    hv[k] = (__bf16)s;
  }
  const size_t base = (size_t)b * F1 + d * KK_;
  const unsigned* hp = (const unsigned*)hv;
  unsigned* dh = (unsigned*)&f_hi[base];
  dh[0] = hp[0]; dh[1] = hp[1]; dh[2] = hp[2];
}

// ---------------------------------------------------------------------------
// K3: 128x128-tile MFMA GEMM with XCD-aware 2D block partition.
// 448 linear blocks; XCD = linear%8 (HW round-robin). Each XCD owns an
// 8bm x 7bn sub-grid -> A panels 3MB + B panels 2.6MB ~ L2-resident.
// ---------------------------------------------------------------------------
__global__ __launch_bounds__(256) void gemm_mfma_kernel(
    const __bf16* __restrict__ f_hi, const __bf16* __restrict__ w_all,
    float* __restrict__ P)
{
  __shared__ __bf16 As[2][128 * 64];
  __shared__ __bf16 Bs[2][128 * 64];
  const int linear = blockIdx.x;
  const int xcd  = linear & 7;
  const int slot = linear >> 3;          // 0..55
  const int bm = (((xcd & 3) << 3) + (slot & 7)) * 128;   // bm-group 0..3
  const int bn = (((xcd >> 2) * 7) + (slot >> 3)) * 128;  // bn-group 0..1
  const int tid = threadIdx.x;
  const int wid = tid >> 6, lane = tid & 63;
  const int wr = wid >> 1, wc = wid & 1;

  const int srow = lane >> 3;                 // 0..7 row within 8-row chunk
  const int skb8 = ((lane & 7) ^ srow) << 3;  // inverse-swizzled src elem off

  const int l15   = lane & 15;
  const int mask  = (lane & 7) << 4;
  const int khalf = (lane >> 4) << 4;
  int offA[4][2], offB[4][2];
#pragma unroll
  for (int m = 0; m < 4; ++m) {
    const int row = wr * 64 + m * 16 + l15;
#pragma unroll
    for (int s = 0; s < 2; ++s)
      offA[m][s] = row * 128 + (((s << 6) | khalf) ^ mask);
  }
#pragma unroll
  for (int n = 0; n < 4; ++n) {
    const int col = wc * 64 + n * 16 + l15;
#pragma unroll
    for (int s = 0; s < 2; ++s)
      offB[n][s] = col * 128 + (((s << 6) | khalf) ^ mask);
  }

  f32x4 acc[4][4] = {};

  auto stage = [&](int it, int buf) {
    const int kl = it * BK;
#pragma unroll
    for (int j = 0; j < 4; ++j) {
      const int q = wid * 4 + j;   // 16 chunks of 8 rows
      gload_lds16(f_hi  + (size_t)(bm + q * 8 + srow) * F1 + kl + skb8, &As[buf][q * 512]);
      gload_lds16(w_all + (size_t)(bn + q * 8 + srow) * F1 + kl + skb8, &Bs[buf][q * 512]);
    }
  };

  stage(0, 0);
  __syncthreads();
  for (int it = 0; it < NIT; ++it) {
    const int cur = it & 1;
    if (it + 1 < NIT) stage(it + 1, cur ^ 1);
    const char* pa = (const char*)As[cur];
    const char* pb = (const char*)Bs[cur];
#pragma unroll
    for (int s = 0; s < 2; ++s) {
      bf16x8 av[4], bv[4];
#pragma unroll
      for (int m = 0; m < 4; ++m) av[m] = *(const bf16x8*)(pa + offA[m][s]);
#pragma unroll
      for (int n = 0; n < 4; ++n) bv[n] = *(const bf16x8*)(pb + offB[n][s]);
#pragma unroll
      for (int m = 0; m < 4; ++m)
#pragma unroll
        for (int n = 0; n < 4; ++n)
          acc[m][n] = __builtin_amdgcn_mfma_f32_16x16x32_bf16(av[m], bv[n], acc[m][n], 0, 0, 0);
    }
    __syncthreads();
  }

  const int r0 = (lane >> 4) << 2;
#pragma unroll
  for (int m = 0; m < 4; ++m)
#pragma unroll
    for (int n = 0; n < 4; ++n)
#pragma unroll
      for (int r = 0; r < 4; ++r)
        P[(size_t)(bm + wr * 64 + m * 16 + r0 + r) * NALL + (bn + wc * 64 + n * 16 + l15)] =
            acc[m][n][r];
}

// ---------------------------------------------------------------------------
// K4: fused epilogue — wave 0: sparsemax over att logits (P cols 0..255)
// into LDS; then all 4 waves: leaf products and output.
// ---------------------------------------------------------------------------
__global__ __launch_bounds__(256) void epilogue_kernel(
    const float* __restrict__ P, const float* __restrict__ catt,
    const float* __restrict__ w_c,
    const float* __restrict__ leaf, float* __restrict__ out)
{
  const int b = blockIdx.x;
  __shared__ float a_val_sh[T_];
  __shared__ unsigned short a_t_sh[T_];
  __shared__ int nact_sh;
  __shared__ float oacc[4][C_];
  const int tid = threadIdx.x;
  const int wid = tid >> 6, lane = tid & 63;

  if (wid == 0) {
    float z[4];
#pragma unroll
    for (int j = 0; j < 4; ++j) {
      const int t = lane + 64 * j;
      z[j] = P[(size_t)b * NALL + t] + catt[t];
    }
    float tau = -1e30f, taun = 0.f;
    int cprev = T_ + 1;
    for (int it = 0; it < 40; ++it) {
      float s = 0.f; int c = 0;
#pragma unroll
      for (int j = 0; j < 4; ++j) if (z[j] > tau) { s += z[j]; c++; }
      s = waveSum(s); c = waveSumI(c);
      taun = (s - 1.0f) / (float)c;
      if (c == cprev) break;
      cprev = c; tau = taun;
    }
    tau = taun;
    float av[4]; int nnz = 0;
#pragma unroll
    for (int j = 0; j < 4; ++j) {
      float a = z[j] - tau; av[j] = a > 0.f ? a : 0.f;
      if (av[j] > 0.f) nnz++;
    }
    int incl = nnz;
#pragma unroll
    for (int off = 1; off < 64; off <<= 1) {
      const int n = __shfl_up(incl, off, 64);
      if (lane >= off) incl += n;
    }
    int pos = incl - nnz;
#pragma unroll
    for (int j = 0; j < 4; ++j) {
      if (av[j] > 0.f) {
        a_val_sh[pos] = av[j];
        a_t_sh[pos] = (unsigned short)(lane + 64 * j);
        pos++;
      }
    }
    if (lane == 63) nact_sh = incl;
  }
  __syncthreads();

  const int nact = nact_sh;
  float o[C_];
#pragma unroll
  for (int c = 0; c < C_; ++c) o[c] = 0.f;

  for (int i = wid; i < nact; i += 4) {
    const int t = (int)a_t_sh[i];
    const float* pp = P + (size_t)b * NALL + T_ + t * DEPTH_;
    const float* wc = w_c + t * DEPTH_;
    float prob = a_val_sh[i];
#pragma unroll
    for (int d = 0; d < DEPTH_; ++d) {
      float pv = wc[d] + pp[d];
      pv = pv < 1e-6f ? 1e-6f : (pv > 1.0f - 1e-6f ? 1.0f - 1e-6f : pv);
      prob *= ((lane >> d) & 1) ? pv : (1.0f - pv);
    }
    const float* lf = leaf + ((size_t)t * 64 + lane) * C_;
#pragma unroll
    for (int c = 0; c < C_; ++c) o[c] += prob * lf[c];
  }
#pragma unroll
  for (int c = 0; c < C_; ++c) o[c] = waveSum(o[c]);
  if (lane == 0) {
#pragma unroll
    for (int c = 0; c < C_; ++c) oacc[wid][c] = o[c];
  }
  __syncthreads();
  if (tid < C_)
    out[(size_t)b * C_ + tid] = oacc[0][tid] + oacc[1][tid] + oacc[2][tid] + oacc[3][tid];
}

// ---------------------------------------------------------------------------
extern "C" void kernel_launch(void* const* d_in, const int* in_sizes, int n_in,
                              void* d_out, int out_size, void* d_ws, size_t ws_size,
                              hipStream_t stream)
{
  const float* x        = (const float*)d_in[0];
  const float* thr      = (const float*)d_in[1];
  const float* log_beta = (const float*)d_in[2];
  const float* sel      = (const float*)d_in[3];
  const float* leaf     = (const float*)d_in[4];
  const float* att_W    = (const float*)d_in[5];
  const float* att_b    = (const float*)d_in[6];
  float* out = (float*)d_out;

  char* ws = (char*)d_ws;
  size_t off = 0;
  auto alloc = [&](size_t bytes) {
    char* p = ws + off;
    off = (off + bytes + 255) & ~(size_t)255;
    return p;
  };
  __bf16* f_hi   = (__bf16*)alloc((size_t)B_ * F1 * 2);        // 12.6 MB
  __bf16* w_all  = (__bf16*)alloc((size_t)NALL * F1 * 2);      //  5.5 MB
  float*  catt   = (float*)alloc((size_t)T_ * 4);
  float*  pc     = (float*)alloc((size_t)NFB * T_ * 4);
  float*  w_c    = (float*)alloc((size_t)NROW * 4);
  float*  P      = (float*)alloc((size_t)B_ * NALL * 4);       // 29.4 MB
  (void)ws_size; (void)in_sizes; (void)n_in; (void)out_size;   // ~48 MB total

  hipLaunchKernelGGL(prep_att_kernel,      dim3(NFB, T_ / 64), dim3(256), 0, stream, att_W, w_all, pc);
  hipLaunchKernelGGL(catt_kernel,          dim3(1),            dim3(256), 0, stream, pc, att_b, catt);
  hipLaunchKernelGGL(sel_sparsemax_kernel, dim3(NROW / 4),     dim3(256), 0, stream, sel, w_all, w_c);
  hipLaunchKernelGGL(f_kernel,             dim3(B_),           dim3(256), 0, stream, x, thr, log_beta, f_hi);
  hipLaunchKernelGGL(gemm_mfma_kernel,     dim3(NBLK),         dim3(256), 0, stream, f_hi, w_all, P);
  hipLaunchKernelGGL(epilogue_kernel,      dim3(B_),           dim3(256), 0, stream, P, catt, w_c, leaf, out);
}